// Round 11
// baseline (353.478 us; speedup 1.0000x reference)
//
#include <hip/hip_runtime.h>

#define HW 16384
#define CC 192
#define C3 576
#define NB 8
#define NH 8

typedef __attribute__((ext_vector_type(8))) short bfrag;
typedef __attribute__((ext_vector_type(4))) float f32x4;
typedef __attribute__((ext_vector_type(4))) unsigned short us4;

#define MFMA16(a, b, c) __builtin_amdgcn_mfma_f32_16x16x32_bf16(a, b, c, 0, 0, 0)

typedef __attribute__((address_space(3))) unsigned int lds_u32;
typedef __attribute__((address_space(1))) unsigned int glb_u32;
__device__ __forceinline__ void gl_lds16(const void* g, void* l) {
  __builtin_amdgcn_global_load_lds((const glb_u32*)g, (lds_u32*)l, 16, 0, 0);
}

__device__ __forceinline__ unsigned short f2bf(float f) {
  unsigned int u = __float_as_uint(f);
  u += 0x7fffu + ((u >> 16) & 1u);
  return (unsigned short)(u >> 16);
}
__device__ __forceinline__ float bf2f(unsigned short s) {
  return __uint_as_float(((unsigned int)s) << 16);
}
__device__ __forceinline__ float bf2f_s(short s) {
  return __uint_as_float(((unsigned int)(unsigned short)s) << 16);
}

// ---------------- workspace layout (bytes) ----------------
#define OFF_XT   0ull
#define SZ_XT    ((size_t)NB * HW * CC * 2)      // x transposed bf16 [b][hw][192]; later reused as VT
#define OFF_WQ   (OFF_XT + SZ_XT)
#define SZ_WQ    ((size_t)C3 * CC * 2)           // W packed into MFMA frag order
#define OFF_QKV  (OFF_WQ + SZ_WQ)
#define SZ_QKV   ((size_t)NB * C3 * HW * 2)      // qkv (pre-dw) bf16 [b][576][hw]
#define OFF_S    (OFF_QKV + SZ_QKV)
#define SZ_S     ((size_t)NB * NH * 32 * 32 * 4) // gram fp32 [b][h][32][32]
#define OFF_SSQ  (OFF_S + SZ_S)
#define SZ_SSQ   ((size_t)NB * 384 * 4)          // sumsq fp32 [b][q:192 | k:192]
#define OFF_M    (OFF_SSQ + SZ_SSQ)
#define SZ_M     ((size_t)NB * CC * CC * 2)      // fused proj*attn, packed frag order

// ---------------- prep: x -> bf16 transposed [b][hw][c] ----------------
__global__ __launch_bounds__(256) void k_xt(const float* __restrict__ x,
                                            unsigned short* __restrict__ xt) {
  __shared__ unsigned short tile[64 * 72];
  const int pb = blockIdx.x * 64;
  const int cb = blockIdx.y * 64;
  const int b  = blockIdx.z;
  const int t  = threadIdx.x;
  {
    const int cl = t >> 2, pl = (t & 3) * 16;
    const float* src = x + ((size_t)b * CC + cb + cl) * HW + pb + pl;
    bfrag v0, v1;
#pragma unroll
    for (int q4 = 0; q4 < 2; ++q4) {
      float4 f = *reinterpret_cast<const float4*>(src + q4 * 4);
      v0[q4 * 4 + 0] = (short)f2bf(f.x); v0[q4 * 4 + 1] = (short)f2bf(f.y);
      v0[q4 * 4 + 2] = (short)f2bf(f.z); v0[q4 * 4 + 3] = (short)f2bf(f.w);
    }
#pragma unroll
    for (int q4 = 0; q4 < 2; ++q4) {
      float4 f = *reinterpret_cast<const float4*>(src + 8 + q4 * 4);
      v1[q4 * 4 + 0] = (short)f2bf(f.x); v1[q4 * 4 + 1] = (short)f2bf(f.y);
      v1[q4 * 4 + 2] = (short)f2bf(f.z); v1[q4 * 4 + 3] = (short)f2bf(f.w);
    }
    *reinterpret_cast<bfrag*>(&tile[cl * 72 + pl]) = v0;
    *reinterpret_cast<bfrag*>(&tile[cl * 72 + pl + 8]) = v1;
  }
  __syncthreads();
  {
    const int pl = t >> 2, cl = (t & 3) * 16;
    bfrag o0, o1;
#pragma unroll
    for (int e = 0; e < 8; ++e) o0[e] = (short)tile[(cl + e) * 72 + pl];
#pragma unroll
    for (int e = 0; e < 8; ++e) o1[e] = (short)tile[(cl + 8 + e) * 72 + pl];
    unsigned short* dst = xt + ((size_t)b * HW + pb + pl) * CC + cb + cl;
    *reinterpret_cast<bfrag*>(dst) = o0;
    *reinterpret_cast<bfrag*>(dst + 8) = o1;
  }
}

// ---------------- prep: pack W into MFMA fragment order ----------------
__global__ __launch_bounds__(256) void k_wpack(const float* __restrict__ w,
                                               unsigned short* __restrict__ wp) {
  const int g = blockIdx.x * 256 + threadIdx.x;
  if (g >= 216 * 64) return;
  const int frag = g >> 6, lane = g & 63;
  const int mb = frag / 24, r = frag % 24, s = r >> 2, i = r & 3;
  const int row = mb * 64 + i * 16 + (lane & 15);
  const int col = s * 32 + (lane >> 4) * 8;
  const float* src = w + (size_t)row * CC + col;
  float4 f0 = *reinterpret_cast<const float4*>(src);
  float4 f1 = *reinterpret_cast<const float4*>(src + 4);
  us4 o0, o1;
  o0[0] = f2bf(f0.x); o0[1] = f2bf(f0.y); o0[2] = f2bf(f0.z); o0[3] = f2bf(f0.w);
  o1[0] = f2bf(f1.x); o1[1] = f2bf(f1.y); o1[2] = f2bf(f1.z); o1[3] = f2bf(f1.w);
  *reinterpret_cast<us4*>(wp + (size_t)g * 8) = o0;
  *reinterpret_cast<us4*>(wp + (size_t)g * 8 + 4) = o1;
}

// ---------------- qkv GEMM (R8-proven) ----------------
__global__ __launch_bounds__(256, 3) void k_gemm_qkv(const unsigned short* __restrict__ Wp,
                                                     const unsigned short* __restrict__ Xt,
                                                     unsigned short* __restrict__ Y) {
  __shared__ __attribute__((aligned(16))) char sB[49152];
  const int nb = blockIdx.x;
  const int b  = blockIdx.y;
  const int tid = threadIdx.x;
  const int wave = tid >> 6, lane = tid & 63;
  const int lrow = lane & 15, lk = (lane >> 4) * 8, lr4 = (lane >> 4) * 4;

  const char* Bc = (const char*)(Xt + ((size_t)b * HW + (size_t)nb * 128) * CC);
#pragma unroll
  for (int t = 0; t < 12; ++t) {
    const int L = wave * 12288 + t * 1024 + lane * 16;
    const int row = L / 384;
    const int rem = L - row * 384;
    gl_lds16(Bc + row * 384 + (rem ^ ((row & 7) << 4)), sB + wave * 12288 + t * 1024);
  }
  asm volatile("s_waitcnt vmcnt(0)" ::: "memory");
  __syncthreads();

  const int swz = (lrow & 7) << 4;
  const int base0 = (wave * 32 + lrow) * 384;
  const f32x4 z4 = {0.f, 0.f, 0.f, 0.f};

#pragma unroll 1
  for (int mb = 0; mb < 9; ++mb) {
    const unsigned short* Wb = Wp + (size_t)mb * 24 * 512;
    bfrag af[6][4];
#pragma unroll
    for (int s = 0; s < 6; ++s)
#pragma unroll
      for (int i = 0; i < 4; ++i)
        af[s][i] = *reinterpret_cast<const bfrag*>(Wb + ((s * 4 + i) * 64 + lane) * 8);

    f32x4 acc[4][2];
#pragma unroll
    for (int i = 0; i < 4; ++i) { acc[i][0] = z4; acc[i][1] = z4; }
#pragma unroll
    for (int s = 0; s < 6; ++s) {
      const int kbs = ((s * 32 + lk) * 2) ^ swz;
      bfrag b0 = *reinterpret_cast<const bfrag*>(sB + base0 + kbs);
      bfrag b1 = *reinterpret_cast<const bfrag*>(sB + base0 + 16 * 384 + kbs);
#pragma unroll
      for (int i = 0; i < 4; ++i) {
        acc[i][0] = MFMA16(b0, af[s][i], acc[i][0]);  // D[px][ch]
        acc[i][1] = MFMA16(b1, af[s][i], acc[i][1]);
      }
    }
    unsigned short* Yb = Y + ((size_t)b * C3 + mb * 64) * HW + nb * 128 + wave * 32;
#pragma unroll
    for (int i = 0; i < 4; ++i) {
      unsigned short* rp = Yb + (size_t)(i * 16 + lrow) * HW;
#pragma unroll
      for (int j = 0; j < 2; ++j) {
        uint2 pk;
        pk.x = (unsigned int)f2bf(acc[i][j][0]) | ((unsigned int)f2bf(acc[i][j][1]) << 16);
        pk.y = (unsigned int)f2bf(acc[i][j][2]) | ((unsigned int)f2bf(acc[i][j][3]) << 16);
        *reinterpret_cast<uint2*>(rp + j * 16 + lr4) = pk;
      }
    }
  }
}

// ---------------- fused dwconv(q,k) + gram + ssq (occupancy package) ----------------
// 256-px chunks (2 image rows), LDS 29.6KB -> 5 blocks/CU; grid (32,8,8)=2048
// blocks; halo values via __shfl (no halo loads). Gram MFMA identical math.
__global__ __launch_bounds__(256, 5) void k_dwgram(const unsigned short* __restrict__ QKV,
                                                   const float* __restrict__ wd,
                                                   float* __restrict__ S,
                                                   float* __restrict__ ssq) {
  __shared__ short lds[56 * 264];  // rows 0..23 q, 24..47 k, 48..55 slack
  const int strip = blockIdx.x, h = blockIdx.y, b = blockIdx.z;  // strip of 512px
  const int tid = threadIdx.x, wave = tid >> 6, lane = tid & 63;
  const int lrow = lane & 15, lk8 = (lane >> 4) * 8, lr4 = (lane >> 4) * 4;
  const size_t qbase = ((size_t)b * C3 + h * 24) * HW;
  const size_t kbase = qbase + (size_t)192 * HW;

  const int p = lane * 4;       // px within 256-chunk
  const int x0 = p & 127;
  const int rowc = p >> 7;      // 0 or 1

  float sqp[6] = {0.f, 0.f, 0.f, 0.f, 0.f, 0.f};
  float skp[6] = {0.f, 0.f, 0.f, 0.f, 0.f, 0.f};
  f32x4 acc[2][2];
  const f32x4 z4 = {0.f, 0.f, 0.f, 0.f};
#pragma unroll
  for (int i = 0; i < 2; ++i) { acc[i][0] = z4; acc[i][1] = z4; }

  auto dwconv4 = [&](const unsigned short* ip, const float* w, int y, float* facc) {
#pragma unroll
    for (int e = 0; e < 4; ++e) facc[e] = 0.f;
#pragma unroll
    for (int dy = 0; dy < 3; ++dy) {
      int yy = y + dy - 1;
      if (yy < 0 || yy > 127) continue;
      const unsigned short* row = ip + yy * 128;
      us4 v = *reinterpret_cast<const us4*>(row + x0);
      float c[4];
#pragma unroll
      for (int e = 0; e < 4; ++e) c[e] = bf2f(v[e]);
      float left = __shfl_up(c[3], 1);
      left = (x0 == 0) ? 0.f : left;      // row start: halo = 0 (SAME padding)
      float right = __shfl_down(c[0], 1);
      right = (x0 == 124) ? 0.f : right;  // row end
      float wl = w[dy * 3 + 0], wc = w[dy * 3 + 1], wr = w[dy * 3 + 2];
      facc[0] += wl * left + wc * c[0] + wr * c[1];
      facc[1] += wl * c[0] + wc * c[1] + wr * c[2];
      facc[2] += wl * c[1] + wc * c[2] + wr * c[3];
      facc[3] += wl * c[2] + wc * c[3] + wr * right;
    }
  };

#pragma unroll 1
  for (int chunk = 0; chunk < 2; ++chunk) {
    const int y = strip * 4 + chunk * 2 + rowc;
#pragma unroll 2
    for (int j = 0; j < 6; ++j) {
      const int c = wave + 4 * j;
      float fq[4], fk[4];
      dwconv4(QKV + qbase + (size_t)c * HW, wd + (h * 24 + c) * 9, y, fq);
      dwconv4(QKV + kbase + (size_t)c * HW, wd + (192 + h * 24 + c) * 9, y, fk);
      {
        us4 o;
        float ss = 0.f;
#pragma unroll
        for (int e = 0; e < 4; ++e) { ss += fq[e] * fq[e]; o[e] = f2bf(fq[e]); }
        sqp[j] += ss;
        *reinterpret_cast<us4*>(&lds[c * 264 + p]) = o;
      }
      {
        us4 o;
        float ss = 0.f;
#pragma unroll
        for (int e = 0; e < 4; ++e) { ss += fk[e] * fk[e]; o[e] = f2bf(fk[e]); }
        skp[j] += ss;
        *reinterpret_cast<us4*>(&lds[(24 + c) * 264 + p]) = o;
      }
    }
    __syncthreads();
#pragma unroll
    for (int ks = 0; ks < 2; ++ks) {
      const int pp = wave * 64 + ks * 32 + lk8;
      bfrag aq[2], bk[2];
#pragma unroll
      for (int i = 0; i < 2; ++i) {
        aq[i] = *reinterpret_cast<const bfrag*>(&lds[(i * 16 + lrow) * 264 + pp]);
        bk[i] = *reinterpret_cast<const bfrag*>(&lds[(24 + i * 16 + lrow) * 264 + pp]);
      }
#pragma unroll
      for (int i = 0; i < 2; ++i)
#pragma unroll
        for (int j2 = 0; j2 < 2; ++j2) acc[i][j2] = MFMA16(aq[i], bk[j2], acc[i][j2]);
    }
    __syncthreads();
  }

  float* Sb = S + (size_t)(b * 8 + h) * 1024;
#pragma unroll
  for (int i = 0; i < 2; ++i)
#pragma unroll
    for (int j2 = 0; j2 < 2; ++j2)
#pragma unroll
      for (int r = 0; r < 4; ++r)
        atomicAdd(&Sb[(i * 16 + lr4 + r) * 32 + j2 * 16 + lrow], acc[i][j2][r]);

#pragma unroll
  for (int j = 0; j < 6; ++j) {
    float v = sqp[j];
    float wv = skp[j];
#pragma unroll
    for (int o = 1; o < 64; o <<= 1) { v += __shfl_xor(v, o); wv += __shfl_xor(wv, o); }
    if (lane == 0) {
      const int c = wave + 4 * j;
      atomicAdd(&ssq[b * 384 + h * 24 + c], v);
      atomicAdd(&ssq[b * 384 + 192 + h * 24 + c], wv);
    }
  }
}

// ---------------- fused dwconv(v) + transpose -> VT[b][hw][192] ----------------
__global__ __launch_bounds__(256) void k_dwvt(const unsigned short* __restrict__ QKV,
                                              const float* __restrict__ wd,
                                              unsigned short* __restrict__ VTo) {
  __shared__ unsigned short tile[64 * 72];
  const int pb = blockIdx.x * 64, cb = blockIdx.y * 64, b = blockIdx.z;
  const int t = threadIdx.x;
  const int y = pb >> 7;
  const int xs = pb & 127;
  {
    const int cl = t >> 2, ps = (t & 3) * 16;
    const int gc = 384 + cb + cl;
    const unsigned short* ip = QKV + ((size_t)b * C3 + gc) * HW;
    const float* w = wd + gc * 9;
    const int x0 = xs + ps;
    float acc[16];
#pragma unroll
    for (int e = 0; e < 16; ++e) acc[e] = 0.f;
#pragma unroll
    for (int dy = 0; dy < 3; ++dy) {
      int yy = y + dy - 1;
      if (yy < 0 || yy > 127) continue;
      const unsigned short* row = ip + yy * 128;
      bfrag v0 = *reinterpret_cast<const bfrag*>(row + x0);
      bfrag v1 = *reinterpret_cast<const bfrag*>(row + x0 + 8);
      float c[16];
#pragma unroll
      for (int e = 0; e < 8; ++e) { c[e] = bf2f_s(v0[e]); c[8 + e] = bf2f_s(v1[e]); }
      float left  = (x0 > 0)   ? bf2f(row[x0 - 1])  : 0.f;
      float right = (x0 < 112) ? bf2f(row[x0 + 16]) : 0.f;
      float wl = w[dy * 3 + 0], wc = w[dy * 3 + 1], wr = w[dy * 3 + 2];
      acc[0] += wl * left + wc * c[0] + wr * c[1];
#pragma unroll
      for (int e = 1; e < 15; ++e) acc[e] += wl * c[e - 1] + wc * c[e] + wr * c[e + 1];
      acc[15] += wl * c[14] + wc * c[15] + wr * right;
    }
    bfrag o0, o1;
#pragma unroll
    for (int e = 0; e < 8; ++e) { o0[e] = (short)f2bf(acc[e]); o1[e] = (short)f2bf(acc[8 + e]); }
    *reinterpret_cast<bfrag*>(&tile[cl * 72 + ps]) = o0;
    *reinterpret_cast<bfrag*>(&tile[cl * 72 + ps + 8]) = o1;
  }
  __syncthreads();
  {
    const int pl = t >> 2, cs = (t & 3) * 16;
    bfrag o0, o1;
#pragma unroll
    for (int e = 0; e < 8; ++e) o0[e] = (short)tile[(cs + e) * 72 + pl];
#pragma unroll
    for (int e = 0; e < 8; ++e) o1[e] = (short)tile[(cs + 8 + e) * 72 + pl];
    unsigned short* dst = VTo + ((size_t)b * HW + pb + pl) * CC + cb + cs;
    *reinterpret_cast<bfrag*>(dst) = o0;
    *reinterpret_cast<bfrag*>(dst + 8) = o1;
  }
}

// ---------------- softmax + M = wproj @ blockdiag(attn), written PACKED ----------------
__global__ __launch_bounds__(64) void k_attn(const float* __restrict__ S,
                                             const float* __restrict__ ssq,
                                             const float* __restrict__ wproj,
                                             const float* __restrict__ temp,
                                             unsigned short* __restrict__ Mp) {
  const int h = blockIdx.x, b = blockIdx.y;
  __shared__ float A[24][25];
  __shared__ float nq[24], nk[24];
  const float* Sb = S + (size_t)(b * 8 + h) * 1024;
  const float* sq = ssq + b * 384 + h * 24;
  const float* sk = ssq + b * 384 + 192 + h * 24;
  const int t = threadIdx.x;
  if (t < 24) {
    nq[t] = fmaxf(sqrtf(sq[t]), 1e-12f);
    nk[t] = fmaxf(sqrtf(sk[t]), 1e-12f);
  }
  __syncthreads();
  if (t < 24) {
    const float tp = temp[h];
    float row[24];
    float mx = -1e30f;
#pragma unroll
    for (int d = 0; d < 24; ++d) {
      row[d] = Sb[t * 32 + d] / (nq[t] * nk[d]) * tp;
      mx = fmaxf(mx, row[d]);
    }
    float s = 0.f;
#pragma unroll
    for (int d = 0; d < 24; ++d) { row[d] = __expf(row[d] - mx); s += row[d]; }
    const float inv = 1.f / s;
#pragma unroll
    for (int d = 0; d < 24; ++d) A[t][d] = row[d] * inv;
  }
  __syncthreads();
  for (int idx = t; idx < 192 * 24; idx += 64) {
    const int o = idx / 24, dd = idx % 24;
    const float* wrow = wproj + o * 192 + h * 24;
    float a = 0.f;
#pragma unroll
    for (int cc = 0; cc < 24; ++cc) a += wrow[cc] * A[cc][dd];
    const int c = h * 24 + dd;
    const int mb = o >> 6, i = (o >> 4) & 3, lr = o & 15;
    const int s = c >> 5, hi = (c >> 3) & 3, e = c & 7;
    const int off = ((mb * 24 + s * 4 + i) * 64 + hi * 16 + lr) * 8 + e;
    Mp[(size_t)b * CC * CC + off] = f2bf(a);
  }
}

// ---------------- out GEMM (R8-proven) ----------------
__global__ __launch_bounds__(256, 3) void k_gemm_out(const unsigned short* __restrict__ Mp,
                                                     const unsigned short* __restrict__ VT,
                                                     float* __restrict__ out) {
  __shared__ __attribute__((aligned(16))) char sB[49152];
  const int nb = blockIdx.x;
  const int b  = blockIdx.y;
  const int tid = threadIdx.x;
  const int wave = tid >> 6, lane = tid & 63;
  const int lrow = lane & 15, lk = (lane >> 4) * 8, lr4 = (lane >> 4) * 4;

  const char* Bc = (const char*)(VT + ((size_t)b * HW + (size_t)nb * 128) * CC);
#pragma unroll
  for (int t = 0; t < 12; ++t) {
    const int L = wave * 12288 + t * 1024 + lane * 16;
    const int row = L / 384;
    const int rem = L - row * 384;
    gl_lds16(Bc + row * 384 + (rem ^ ((row & 7) << 4)), sB + wave * 12288 + t * 1024);
  }
  asm volatile("s_waitcnt vmcnt(0)" ::: "memory");
  __syncthreads();

  const int swz = (lrow & 7) << 4;
  const int base0 = (wave * 32 + lrow) * 384;
  const f32x4 z4 = {0.f, 0.f, 0.f, 0.f};

#pragma unroll 1
  for (int mb = 0; mb < 3; ++mb) {
    const unsigned short* Mb = Mp + (size_t)b * CC * CC + (size_t)mb * 24 * 512;
    bfrag af[6][4];
#pragma unroll
    for (int s = 0; s < 6; ++s)
#pragma unroll
      for (int i = 0; i < 4; ++i)
        af[s][i] = *reinterpret_cast<const bfrag*>(Mb + ((s * 4 + i) * 64 + lane) * 8);

    f32x4 acc[4][2];
#pragma unroll
    for (int i = 0; i < 4; ++i) { acc[i][0] = z4; acc[i][1] = z4; }
#pragma unroll
    for (int s = 0; s < 6; ++s) {
      const int kbs = ((s * 32 + lk) * 2) ^ swz;
      bfrag b0 = *reinterpret_cast<const bfrag*>(sB + base0 + kbs);
      bfrag b1 = *reinterpret_cast<const bfrag*>(sB + base0 + 16 * 384 + kbs);
#pragma unroll
      for (int i = 0; i < 4; ++i) {
        acc[i][0] = MFMA16(b0, af[s][i], acc[i][0]);  // D[px][ch]
        acc[i][1] = MFMA16(b1, af[s][i], acc[i][1]);
      }
    }
    float* Ob = out + ((size_t)b * CC + mb * 64) * HW + nb * 128 + wave * 32;
#pragma unroll
    for (int i = 0; i < 4; ++i) {
      float* rp = Ob + (size_t)(i * 16 + lrow) * HW;
#pragma unroll
      for (int j = 0; j < 2; ++j)
        *reinterpret_cast<f32x4*>(rp + j * 16 + lr4) = acc[i][j];
    }
  }
}

extern "C" void kernel_launch(void* const* d_in, const int* in_sizes, int n_in,
                              void* d_out, int out_size, void* d_ws, size_t ws_size,
                              hipStream_t stream) {
  const float* x      = (const float*)d_in[0];
  const float* w_qkv  = (const float*)d_in[1];
  const float* w_dw   = (const float*)d_in[2];
  const float* w_proj = (const float*)d_in[3];
  const float* temp   = (const float*)d_in[4];
  float* out = (float*)d_out;
  char* ws = (char*)d_ws;

  unsigned short* XT   = (unsigned short*)(ws + OFF_XT);
  unsigned short* VT   = (unsigned short*)(ws + OFF_XT);  // reuse: XT dead after qkv GEMM
  unsigned short* WP   = (unsigned short*)(ws + OFF_WQ);
  unsigned short* QKV  = (unsigned short*)(ws + OFF_QKV);
  float* S   = (float*)(ws + OFF_S);
  float* SSQ = (float*)(ws + OFF_SSQ);
  unsigned short* MP  = (unsigned short*)(ws + OFF_M);

  hipMemsetAsync(ws + OFF_S, 0, SZ_S + SZ_SSQ, stream);
  k_wpack<<<54, 256, 0, stream>>>(w_qkv, WP);
  k_xt<<<dim3(HW / 64, CC / 64, NB), 256, 0, stream>>>(x, XT);
  k_gemm_qkv<<<dim3(HW / 128, NB), 256, 0, stream>>>(WP, XT, QKV);
  k_dwgram<<<dim3(32, NH, NB), 256, 0, stream>>>(QKV, w_dw, S, SSQ);
  k_dwvt<<<dim3(HW / 64, 3, NB), 256, 0, stream>>>(QKV, w_dw, VT);
  k_attn<<<dim3(NH, NB), 64, 0, stream>>>(S, SSQ, w_proj, temp, MP);
  k_gemm_out<<<dim3(HW / 128, NB), 256, 0, stream>>>(MP, VT, out);
}

// Round 12
// 334.072 us; speedup vs baseline: 1.0581x; 1.0581x over previous
//
#include <hip/hip_runtime.h>

#define HW 16384
#define CC 192
#define C3 576
#define NB 8
#define NH 8

typedef __attribute__((ext_vector_type(8))) short bfrag;
typedef __attribute__((ext_vector_type(4))) float f32x4;
typedef __attribute__((ext_vector_type(4))) unsigned short us4;

#define MFMA16(a, b, c) __builtin_amdgcn_mfma_f32_16x16x32_bf16(a, b, c, 0, 0, 0)

typedef __attribute__((address_space(3))) unsigned int lds_u32;
typedef __attribute__((address_space(1))) unsigned int glb_u32;
__device__ __forceinline__ void gl_lds16(const void* g, void* l) {
  __builtin_amdgcn_global_load_lds((const glb_u32*)g, (lds_u32*)l, 16, 0, 0);
}

__device__ __forceinline__ unsigned short f2bf(float f) {
  unsigned int u = __float_as_uint(f);
  u += 0x7fffu + ((u >> 16) & 1u);
  return (unsigned short)(u >> 16);
}
__device__ __forceinline__ float bf2f(unsigned short s) {
  return __uint_as_float(((unsigned int)s) << 16);
}
__device__ __forceinline__ float bf2f_s(short s) {
  return __uint_as_float(((unsigned int)(unsigned short)s) << 16);
}

// ---------------- workspace layout (bytes) ----------------
#define OFF_XT   0ull
#define SZ_XT    ((size_t)NB * HW * CC * 2)      // x transposed bf16 [b][hw][192]; later reused as VT
#define OFF_WQ   (OFF_XT + SZ_XT)
#define SZ_WQ    ((size_t)C3 * CC * 2)           // W packed into MFMA frag order
#define OFF_QKV  (OFF_WQ + SZ_WQ)
#define SZ_QKV   ((size_t)NB * C3 * HW * 2)      // qkv (pre-dw) bf16 [b][576][hw]
#define OFF_QKD  (OFF_QKV + SZ_QKV)
#define SZ_QKD   ((size_t)NB * 384 * HW * 2)     // post-dw q,k only [b][384][hw]
#define OFF_S    (OFF_QKD + SZ_QKD)
#define SZ_S     ((size_t)NB * NH * 32 * 32 * 4) // gram fp32 [b][h][32][32]
#define OFF_SSQ  (OFF_S + SZ_S)
#define SZ_SSQ   ((size_t)NB * 384 * 4)          // sumsq fp32 [b][q:192 | k:192]
#define OFF_M    (OFF_SSQ + SZ_SSQ)
#define SZ_M     ((size_t)NB * CC * CC * 2)      // fused proj*attn, packed frag order

// ---------------- prep: x -> bf16 transposed [b][hw][c] ----------------
__global__ __launch_bounds__(256) void k_xt(const float* __restrict__ x,
                                            unsigned short* __restrict__ xt) {
  __shared__ unsigned short tile[64 * 72];
  const int pb = blockIdx.x * 64;
  const int cb = blockIdx.y * 64;
  const int b  = blockIdx.z;
  const int t  = threadIdx.x;
  {
    const int cl = t >> 2, pl = (t & 3) * 16;
    const float* src = x + ((size_t)b * CC + cb + cl) * HW + pb + pl;
    bfrag v0, v1;
#pragma unroll
    for (int q4 = 0; q4 < 2; ++q4) {
      float4 f = *reinterpret_cast<const float4*>(src + q4 * 4);
      v0[q4 * 4 + 0] = (short)f2bf(f.x); v0[q4 * 4 + 1] = (short)f2bf(f.y);
      v0[q4 * 4 + 2] = (short)f2bf(f.z); v0[q4 * 4 + 3] = (short)f2bf(f.w);
    }
#pragma unroll
    for (int q4 = 0; q4 < 2; ++q4) {
      float4 f = *reinterpret_cast<const float4*>(src + 8 + q4 * 4);
      v1[q4 * 4 + 0] = (short)f2bf(f.x); v1[q4 * 4 + 1] = (short)f2bf(f.y);
      v1[q4 * 4 + 2] = (short)f2bf(f.z); v1[q4 * 4 + 3] = (short)f2bf(f.w);
    }
    *reinterpret_cast<bfrag*>(&tile[cl * 72 + pl]) = v0;
    *reinterpret_cast<bfrag*>(&tile[cl * 72 + pl + 8]) = v1;
  }
  __syncthreads();
  {
    const int pl = t >> 2, cl = (t & 3) * 16;
    bfrag o0, o1;
#pragma unroll
    for (int e = 0; e < 8; ++e) o0[e] = (short)tile[(cl + e) * 72 + pl];
#pragma unroll
    for (int e = 0; e < 8; ++e) o1[e] = (short)tile[(cl + 8 + e) * 72 + pl];
    unsigned short* dst = xt + ((size_t)b * HW + pb + pl) * CC + cb + cl;
    *reinterpret_cast<bfrag*>(dst) = o0;
    *reinterpret_cast<bfrag*>(dst + 8) = o1;
  }
}

// ---------------- prep: pack W into MFMA fragment order ----------------
__global__ __launch_bounds__(256) void k_wpack(const float* __restrict__ w,
                                               unsigned short* __restrict__ wp) {
  const int g = blockIdx.x * 256 + threadIdx.x;
  if (g >= 216 * 64) return;
  const int frag = g >> 6, lane = g & 63;
  const int mb = frag / 24, r = frag % 24, s = r >> 2, i = r & 3;
  const int row = mb * 64 + i * 16 + (lane & 15);
  const int col = s * 32 + (lane >> 4) * 8;
  const float* src = w + (size_t)row * CC + col;
  float4 f0 = *reinterpret_cast<const float4*>(src);
  float4 f1 = *reinterpret_cast<const float4*>(src + 4);
  us4 o0, o1;
  o0[0] = f2bf(f0.x); o0[1] = f2bf(f0.y); o0[2] = f2bf(f0.z); o0[3] = f2bf(f0.w);
  o1[0] = f2bf(f1.x); o1[1] = f2bf(f1.y); o1[2] = f2bf(f1.z); o1[3] = f2bf(f1.w);
  *reinterpret_cast<us4*>(wp + (size_t)g * 8) = o0;
  *reinterpret_cast<us4*>(wp + (size_t)g * 8 + 4) = o1;
}

// ---------------- qkv GEMM (R8-proven) ----------------
__global__ __launch_bounds__(256, 3) void k_gemm_qkv(const unsigned short* __restrict__ Wp,
                                                     const unsigned short* __restrict__ Xt,
                                                     unsigned short* __restrict__ Y) {
  __shared__ __attribute__((aligned(16))) char sB[49152];
  const int nb = blockIdx.x;
  const int b  = blockIdx.y;
  const int tid = threadIdx.x;
  const int wave = tid >> 6, lane = tid & 63;
  const int lrow = lane & 15, lk = (lane >> 4) * 8, lr4 = (lane >> 4) * 4;

  const char* Bc = (const char*)(Xt + ((size_t)b * HW + (size_t)nb * 128) * CC);
#pragma unroll
  for (int t = 0; t < 12; ++t) {
    const int L = wave * 12288 + t * 1024 + lane * 16;
    const int row = L / 384;
    const int rem = L - row * 384;
    gl_lds16(Bc + row * 384 + (rem ^ ((row & 7) << 4)), sB + wave * 12288 + t * 1024);
  }
  asm volatile("s_waitcnt vmcnt(0)" ::: "memory");
  __syncthreads();

  const int swz = (lrow & 7) << 4;
  const int base0 = (wave * 32 + lrow) * 384;
  const f32x4 z4 = {0.f, 0.f, 0.f, 0.f};

#pragma unroll 1
  for (int mb = 0; mb < 9; ++mb) {
    const unsigned short* Wb = Wp + (size_t)mb * 24 * 512;
    bfrag af[6][4];
#pragma unroll
    for (int s = 0; s < 6; ++s)
#pragma unroll
      for (int i = 0; i < 4; ++i)
        af[s][i] = *reinterpret_cast<const bfrag*>(Wb + ((s * 4 + i) * 64 + lane) * 8);

    f32x4 acc[4][2];
#pragma unroll
    for (int i = 0; i < 4; ++i) { acc[i][0] = z4; acc[i][1] = z4; }
#pragma unroll
    for (int s = 0; s < 6; ++s) {
      const int kbs = ((s * 32 + lk) * 2) ^ swz;
      bfrag b0 = *reinterpret_cast<const bfrag*>(sB + base0 + kbs);
      bfrag b1 = *reinterpret_cast<const bfrag*>(sB + base0 + 16 * 384 + kbs);
#pragma unroll
      for (int i = 0; i < 4; ++i) {
        acc[i][0] = MFMA16(b0, af[s][i], acc[i][0]);  // D[px][ch]
        acc[i][1] = MFMA16(b1, af[s][i], acc[i][1]);
      }
    }
    unsigned short* Yb = Y + ((size_t)b * C3 + mb * 64) * HW + nb * 128 + wave * 32;
#pragma unroll
    for (int i = 0; i < 4; ++i) {
      unsigned short* rp = Yb + (size_t)(i * 16 + lrow) * HW;
#pragma unroll
      for (int j = 0; j < 2; ++j) {
        uint2 pk;
        pk.x = (unsigned int)f2bf(acc[i][j][0]) | ((unsigned int)f2bf(acc[i][j][1]) << 16);
        pk.y = (unsigned int)f2bf(acc[i][j][2]) | ((unsigned int)f2bf(acc[i][j][3]) << 16);
        *reinterpret_cast<uint2*>(rp + j * 16 + lr4) = pk;
      }
    }
  }
}

// ---------------- depthwise 3x3 SAME on q,k channels only (R8-proven structure) ----------------
__global__ __launch_bounds__(256) void k_dwconv(const unsigned short* __restrict__ in,
                                                const float* __restrict__ wd,
                                                unsigned short* __restrict__ outb) {
  const int strip = blockIdx.x;  // 8 strips of 2048 px
  const int ch = blockIdx.y;     // 384 (q,k channels)
  const int b = blockIdx.z;
  const int t = threadIdx.x;
  const unsigned short* ip = in + ((size_t)b * C3 + ch) * HW;
  const float* w = wd + ch * 9;
  const int p = strip * 2048 + t * 8;
  const int y = p >> 7, x0 = p & 127;
  float acc[8] = {0.f, 0.f, 0.f, 0.f, 0.f, 0.f, 0.f, 0.f};
#pragma unroll
  for (int dy = 0; dy < 3; ++dy) {
    int yy = y + dy - 1;
    if (yy < 0 || yy > 127) continue;
    const unsigned short* row = ip + yy * 128;
    bfrag v = *reinterpret_cast<const bfrag*>(row + x0);
    float c[8];
#pragma unroll
    for (int e = 0; e < 8; ++e) c[e] = bf2f_s(v[e]);
    float left  = (x0 > 0)   ? bf2f(row[x0 - 1]) : 0.f;
    float right = (x0 < 120) ? bf2f(row[x0 + 8]) : 0.f;
    float wl = w[dy * 3 + 0], wc = w[dy * 3 + 1], wr = w[dy * 3 + 2];
    acc[0] += wl * left + wc * c[0] + wr * c[1];
#pragma unroll
    for (int e = 1; e < 7; ++e) acc[e] += wl * c[e - 1] + wc * c[e] + wr * c[e + 1];
    acc[7] += wl * c[6] + wc * c[7] + wr * right;
  }
  unsigned short* op = outb + ((size_t)b * 384 + ch) * HW + p;
  bfrag o;
#pragma unroll
  for (int e = 0; e < 8; ++e) o[e] = (short)f2bf(acc[e]);
  *reinterpret_cast<bfrag*>(op) = o;
}

// ---------------- gram from QKD [b][384][hw] (R1-proven, re-strided) ----------------
__global__ __launch_bounds__(256) void k_gram(const unsigned short* __restrict__ Qd,
                                              float* __restrict__ S,
                                              float* __restrict__ ssq) {
  const int chunk = blockIdx.x;  // 16 chunks of 1024 px
  const int h = blockIdx.y, b = blockIdx.z;
  const int tid = threadIdx.x, wave = tid >> 6, lane = tid & 63;
  const int lrow = lane & 15, lk8 = (lane >> 4) * 8;
  const unsigned short* qb = Qd + ((size_t)b * 384 + h * 24) * HW;
  const unsigned short* kb = qb + (size_t)192 * HW;
  const int p0 = chunk * 1024 + wave * 256;
  f32x4 acc[2][2];
  const f32x4 z4 = {0.f, 0.f, 0.f, 0.f};
#pragma unroll
  for (int i = 0; i < 2; ++i)
#pragma unroll
    for (int j = 0; j < 2; ++j) acc[i][j] = z4;
  float sq[2] = {0.f, 0.f}, sk[2] = {0.f, 0.f};
  for (int s = 0; s < 8; ++s) {
    const int pp = p0 + s * 32 + lk8;
    bfrag aq[2], bk[2];
#pragma unroll
    for (int i = 0; i < 2; ++i) {
      aq[i] = *reinterpret_cast<const bfrag*>(qb + (size_t)(i * 16 + lrow) * HW + pp);
      bk[i] = *reinterpret_cast<const bfrag*>(kb + (size_t)(i * 16 + lrow) * HW + pp);
    }
#pragma unroll
    for (int i = 0; i < 2; ++i) {
#pragma unroll
      for (int e = 0; e < 8; ++e) {
        float qv = bf2f_s(aq[i][e]); sq[i] += qv * qv;
        float kv = bf2f_s(bk[i][e]); sk[i] += kv * kv;
      }
    }
#pragma unroll
    for (int i = 0; i < 2; ++i)
#pragma unroll
      for (int j = 0; j < 2; ++j) acc[i][j] = MFMA16(aq[i], bk[j], acc[i][j]);
  }
  float* Sb = S + (size_t)(b * 8 + h) * 1024;
  const int lr4 = (lane >> 4) * 4;
#pragma unroll
  for (int i = 0; i < 2; ++i)
#pragma unroll
    for (int j = 0; j < 2; ++j)
#pragma unroll
      for (int r = 0; r < 4; ++r)
        atomicAdd(&Sb[(i * 16 + lr4 + r) * 32 + j * 16 + lrow], acc[i][j][r]);
#pragma unroll
  for (int i = 0; i < 2; ++i) {
    float v = sq[i];
    v += __shfl_xor(v, 16); v += __shfl_xor(v, 32);
    float wv = sk[i];
    wv += __shfl_xor(wv, 16); wv += __shfl_xor(wv, 32);
    const int c = i * 16 + lrow;
    if ((lane >> 4) == 0 && c < 24) {
      atomicAdd(&ssq[b * 384 + h * 24 + c], v);
      atomicAdd(&ssq[b * 384 + 192 + h * 24 + c], wv);
    }
  }
}

// ---------------- fused dwconv(v) + transpose -> VT[b][hw][192] (R9-proven) ----------------
__global__ __launch_bounds__(256) void k_dwvt(const unsigned short* __restrict__ QKV,
                                              const float* __restrict__ wd,
                                              unsigned short* __restrict__ VTo) {
  __shared__ unsigned short tile[64 * 72];
  const int pb = blockIdx.x * 64, cb = blockIdx.y * 64, b = blockIdx.z;
  const int t = threadIdx.x;
  const int y = pb >> 7;
  const int xs = pb & 127;
  {
    const int cl = t >> 2, ps = (t & 3) * 16;
    const int gc = 384 + cb + cl;
    const unsigned short* ip = QKV + ((size_t)b * C3 + gc) * HW;
    const float* w = wd + gc * 9;
    const int x0 = xs + ps;
    float acc[16];
#pragma unroll
    for (int e = 0; e < 16; ++e) acc[e] = 0.f;
#pragma unroll
    for (int dy = 0; dy < 3; ++dy) {
      int yy = y + dy - 1;
      if (yy < 0 || yy > 127) continue;
      const unsigned short* row = ip + yy * 128;
      bfrag v0 = *reinterpret_cast<const bfrag*>(row + x0);
      bfrag v1 = *reinterpret_cast<const bfrag*>(row + x0 + 8);
      float c[16];
#pragma unroll
      for (int e = 0; e < 8; ++e) { c[e] = bf2f_s(v0[e]); c[8 + e] = bf2f_s(v1[e]); }
      float left  = (x0 > 0)   ? bf2f(row[x0 - 1])  : 0.f;
      float right = (x0 < 112) ? bf2f(row[x0 + 16]) : 0.f;
      float wl = w[dy * 3 + 0], wc = w[dy * 3 + 1], wr = w[dy * 3 + 2];
      acc[0] += wl * left + wc * c[0] + wr * c[1];
#pragma unroll
      for (int e = 1; e < 15; ++e) acc[e] += wl * c[e - 1] + wc * c[e] + wr * c[e + 1];
      acc[15] += wl * c[14] + wc * c[15] + wr * right;
    }
    bfrag o0, o1;
#pragma unroll
    for (int e = 0; e < 8; ++e) { o0[e] = (short)f2bf(acc[e]); o1[e] = (short)f2bf(acc[8 + e]); }
    *reinterpret_cast<bfrag*>(&tile[cl * 72 + ps]) = o0;
    *reinterpret_cast<bfrag*>(&tile[cl * 72 + ps + 8]) = o1;
  }
  __syncthreads();
  {
    const int pl = t >> 2, cs = (t & 3) * 16;
    bfrag o0, o1;
#pragma unroll
    for (int e = 0; e < 8; ++e) o0[e] = (short)tile[(cs + e) * 72 + pl];
#pragma unroll
    for (int e = 0; e < 8; ++e) o1[e] = (short)tile[(cs + 8 + e) * 72 + pl];
    unsigned short* dst = VTo + ((size_t)b * HW + pb + pl) * CC + cb + cs;
    *reinterpret_cast<bfrag*>(dst) = o0;
    *reinterpret_cast<bfrag*>(dst + 8) = o1;
  }
}

// ---------------- softmax + M = wproj @ blockdiag(attn), written PACKED ----------------
__global__ __launch_bounds__(64) void k_attn(const float* __restrict__ S,
                                             const float* __restrict__ ssq,
                                             const float* __restrict__ wproj,
                                             const float* __restrict__ temp,
                                             unsigned short* __restrict__ Mp) {
  const int h = blockIdx.x, b = blockIdx.y;
  __shared__ float A[24][25];
  __shared__ float nq[24], nk[24];
  const float* Sb = S + (size_t)(b * 8 + h) * 1024;
  const float* sq = ssq + b * 384 + h * 24;
  const float* sk = ssq + b * 384 + 192 + h * 24;
  const int t = threadIdx.x;
  if (t < 24) {
    nq[t] = fmaxf(sqrtf(sq[t]), 1e-12f);
    nk[t] = fmaxf(sqrtf(sk[t]), 1e-12f);
  }
  __syncthreads();
  if (t < 24) {
    const float tp = temp[h];
    float row[24];
    float mx = -1e30f;
#pragma unroll
    for (int d = 0; d < 24; ++d) {
      row[d] = Sb[t * 32 + d] / (nq[t] * nk[d]) * tp;
      mx = fmaxf(mx, row[d]);
    }
    float s = 0.f;
#pragma unroll
    for (int d = 0; d < 24; ++d) { row[d] = __expf(row[d] - mx); s += row[d]; }
    const float inv = 1.f / s;
#pragma unroll
    for (int d = 0; d < 24; ++d) A[t][d] = row[d] * inv;
  }
  __syncthreads();
  for (int idx = t; idx < 192 * 24; idx += 64) {
    const int o = idx / 24, dd = idx % 24;
    const float* wrow = wproj + o * 192 + h * 24;
    float a = 0.f;
#pragma unroll
    for (int cc = 0; cc < 24; ++cc) a += wrow[cc] * A[cc][dd];
    const int c = h * 24 + dd;
    const int mb = o >> 6, i = (o >> 4) & 3, lr = o & 15;
    const int s = c >> 5, hi = (c >> 3) & 3, e = c & 7;
    const int off = ((mb * 24 + s * 4 + i) * 64 + hi * 16 + lr) * 8 + e;
    Mp[(size_t)b * CC * CC + off] = f2bf(a);
  }
}

// ---------------- out GEMM (R8-proven) ----------------
__global__ __launch_bounds__(256, 3) void k_gemm_out(const unsigned short* __restrict__ Mp,
                                                     const unsigned short* __restrict__ VT,
                                                     float* __restrict__ out) {
  __shared__ __attribute__((aligned(16))) char sB[49152];
  const int nb = blockIdx.x;
  const int b  = blockIdx.y;
  const int tid = threadIdx.x;
  const int wave = tid >> 6, lane = tid & 63;
  const int lrow = lane & 15, lk = (lane >> 4) * 8, lr4 = (lane >> 4) * 4;

  const char* Bc = (const char*)(VT + ((size_t)b * HW + (size_t)nb * 128) * CC);
#pragma unroll
  for (int t = 0; t < 12; ++t) {
    const int L = wave * 12288 + t * 1024 + lane * 16;
    const int row = L / 384;
    const int rem = L - row * 384;
    gl_lds16(Bc + row * 384 + (rem ^ ((row & 7) << 4)), sB + wave * 12288 + t * 1024);
  }
  asm volatile("s_waitcnt vmcnt(0)" ::: "memory");
  __syncthreads();

  const int swz = (lrow & 7) << 4;
  const int base0 = (wave * 32 + lrow) * 384;
  const f32x4 z4 = {0.f, 0.f, 0.f, 0.f};

#pragma unroll 1
  for (int mb = 0; mb < 3; ++mb) {
    const unsigned short* Mb = Mp + (size_t)b * CC * CC + (size_t)mb * 24 * 512;
    bfrag af[6][4];
#pragma unroll
    for (int s = 0; s < 6; ++s)
#pragma unroll
      for (int i = 0; i < 4; ++i)
        af[s][i] = *reinterpret_cast<const bfrag*>(Mb + ((s * 4 + i) * 64 + lane) * 8);

    f32x4 acc[4][2];
#pragma unroll
    for (int i = 0; i < 4; ++i) { acc[i][0] = z4; acc[i][1] = z4; }
#pragma unroll
    for (int s = 0; s < 6; ++s) {
      const int kbs = ((s * 32 + lk) * 2) ^ swz;
      bfrag b0 = *reinterpret_cast<const bfrag*>(sB + base0 + kbs);
      bfrag b1 = *reinterpret_cast<const bfrag*>(sB + base0 + 16 * 384 + kbs);
#pragma unroll
      for (int i = 0; i < 4; ++i) {
        acc[i][0] = MFMA16(b0, af[s][i], acc[i][0]);  // D[px][ch]
        acc[i][1] = MFMA16(b1, af[s][i], acc[i][1]);
      }
    }
    float* Ob = out + ((size_t)b * CC + mb * 64) * HW + nb * 128 + wave * 32;
#pragma unroll
    for (int i = 0; i < 4; ++i) {
      float* rp = Ob + (size_t)(i * 16 + lrow) * HW;
#pragma unroll
      for (int j = 0; j < 2; ++j)
        *reinterpret_cast<f32x4*>(rp + j * 16 + lr4) = acc[i][j];
    }
  }
}

extern "C" void kernel_launch(void* const* d_in, const int* in_sizes, int n_in,
                              void* d_out, int out_size, void* d_ws, size_t ws_size,
                              hipStream_t stream) {
  const float* x      = (const float*)d_in[0];
  const float* w_qkv  = (const float*)d_in[1];
  const float* w_dw   = (const float*)d_in[2];
  const float* w_proj = (const float*)d_in[3];
  const float* temp   = (const float*)d_in[4];
  float* out = (float*)d_out;
  char* ws = (char*)d_ws;

  unsigned short* XT   = (unsigned short*)(ws + OFF_XT);
  unsigned short* VT   = (unsigned short*)(ws + OFF_XT);  // reuse: XT dead after qkv GEMM
  unsigned short* WP   = (unsigned short*)(ws + OFF_WQ);
  unsigned short* QKV  = (unsigned short*)(ws + OFF_QKV);
  unsigned short* QKD  = (unsigned short*)(ws + OFF_QKD);
  float* S   = (float*)(ws + OFF_S);
  float* SSQ = (float*)(ws + OFF_SSQ);
  unsigned short* MP  = (unsigned short*)(ws + OFF_M);

  hipMemsetAsync(ws + OFF_S, 0, SZ_S + SZ_SSQ, stream);
  k_wpack<<<54, 256, 0, stream>>>(w_qkv, WP);
  k_xt<<<dim3(HW / 64, CC / 64, NB), 256, 0, stream>>>(x, XT);
  k_gemm_qkv<<<dim3(HW / 128, NB), 256, 0, stream>>>(WP, XT, QKV);
  k_dwconv<<<dim3(8, 384, NB), 256, 0, stream>>>(QKV, w_dw, QKD);
  k_dwvt<<<dim3(HW / 64, 3, NB), 256, 0, stream>>>(QKV, w_dw, VT);
  k_gram<<<dim3(16, NH, NB), 256, 0, stream>>>(QKD, S, SSQ);
  k_attn<<<dim3(NH, NB), 64, 0, stream>>>(S, SSQ, w_proj, temp, MP);
  k_gemm_out<<<dim3(HW / 128, NB), 256, 0, stream>>>(MP, VT, out);
}

// Round 13
// 322.086 us; speedup vs baseline: 1.0975x; 1.0372x over previous
//
#include <hip/hip_runtime.h>

#define HW 16384
#define CC 192
#define C3 576
#define NB 8
#define NH 8

typedef __attribute__((ext_vector_type(8))) short bfrag;
typedef __attribute__((ext_vector_type(4))) float f32x4;
typedef __attribute__((ext_vector_type(4))) unsigned short us4;

#define MFMA16(a, b, c) __builtin_amdgcn_mfma_f32_16x16x32_bf16(a, b, c, 0, 0, 0)

__device__ __forceinline__ unsigned short f2bf(float f) {
  unsigned int u = __float_as_uint(f);
  u += 0x7fffu + ((u >> 16) & 1u);
  return (unsigned short)(u >> 16);
}
__device__ __forceinline__ float bf2f(unsigned short s) {
  return __uint_as_float(((unsigned int)s) << 16);
}
__device__ __forceinline__ float bf2f_s(short s) {
  return __uint_as_float(((unsigned int)(unsigned short)s) << 16);
}

// fragment-order address (elements) for B operands:
// px_in_tile = w*32 + j*16 + (lane&15); ch = s*32 + ((lane>>4)&3)*8 + e
__device__ __forceinline__ size_t faddr(int b, int tile, int w, int j, int s, int lane) {
  return ((((((size_t)b * 128 + tile) * 4 + w) * 2 + j) * 6 + s) * 512 + (size_t)lane * 8);
}

// ---------------- workspace layout (bytes) ----------------
#define OFF_XT   0ull
#define SZ_XT    ((size_t)NB * HW * CC * 2)      // x bf16 in FRAG order; later reused as VT (frag order)
#define OFF_WQ   (OFF_XT + SZ_XT)
#define SZ_WQ    ((size_t)C3 * CC * 2)           // W packed into MFMA frag order
#define OFF_QKV  (OFF_WQ + SZ_WQ)
#define SZ_QKV   ((size_t)NB * C3 * HW * 2)      // qkv (pre-dw) bf16 [b][576][hw]
#define OFF_QKD  (OFF_QKV + SZ_QKV)
#define SZ_QKD   ((size_t)NB * 384 * HW * 2)     // post-dw q,k only [b][384][hw]
#define OFF_S    (OFF_QKD + SZ_QKD)
#define SZ_S     ((size_t)NB * NH * 32 * 32 * 4) // gram fp32 [b][h][32][32]
#define OFF_SSQ  (OFF_S + SZ_S)
#define SZ_SSQ   ((size_t)NB * 384 * 4)          // sumsq fp32 [b][q:192 | k:192]
#define OFF_M    (OFF_SSQ + SZ_SSQ)
#define SZ_M     ((size_t)NB * CC * CC * 2)      // fused proj*attn, packed frag order

// ---------------- prep: x -> bf16 FRAG-ORDER [b][tile][w][j][s][lane][8] ----------------
__global__ __launch_bounds__(256) void k_xt(const float* __restrict__ x,
                                            unsigned short* __restrict__ xb) {
  __shared__ unsigned short tile[64 * 72];
  const int pb = blockIdx.x * 64;
  const int cb = blockIdx.y * 64;
  const int b  = blockIdx.z;
  const int t  = threadIdx.x;
  {
    const int cl = t >> 2, pl = (t & 3) * 16;
    const float* src = x + ((size_t)b * CC + cb + cl) * HW + pb + pl;
    bfrag v0, v1;
#pragma unroll
    for (int q4 = 0; q4 < 2; ++q4) {
      float4 f = *reinterpret_cast<const float4*>(src + q4 * 4);
      v0[q4 * 4 + 0] = (short)f2bf(f.x); v0[q4 * 4 + 1] = (short)f2bf(f.y);
      v0[q4 * 4 + 2] = (short)f2bf(f.z); v0[q4 * 4 + 3] = (short)f2bf(f.w);
    }
#pragma unroll
    for (int q4 = 0; q4 < 2; ++q4) {
      float4 f = *reinterpret_cast<const float4*>(src + 8 + q4 * 4);
      v1[q4 * 4 + 0] = (short)f2bf(f.x); v1[q4 * 4 + 1] = (short)f2bf(f.y);
      v1[q4 * 4 + 2] = (short)f2bf(f.z); v1[q4 * 4 + 3] = (short)f2bf(f.w);
    }
    *reinterpret_cast<bfrag*>(&tile[cl * 72 + pl]) = v0;
    *reinterpret_cast<bfrag*>(&tile[cl * 72 + pl + 8]) = v1;
  }
  __syncthreads();
  {
    const int pl = t >> 2, cl = (t & 3) * 16;
    bfrag o0, o1;
#pragma unroll
    for (int e = 0; e < 8; ++e) o0[e] = (short)tile[(cl + e) * 72 + pl];
#pragma unroll
    for (int e = 0; e < 8; ++e) o1[e] = (short)tile[(cl + 8 + e) * 72 + pl];
    const int P = pb + pl, ch0 = cb + cl;
    const int ti = P >> 7, pit = P & 127;
    const int w = pit >> 5, j = (pit >> 4) & 1, pxl = pit & 15;
    const int s0 = ch0 >> 5, kh0 = (ch0 >> 3) & 3;
    const int ch1 = ch0 + 8, s1 = ch1 >> 5, kh1 = (ch1 >> 3) & 3;
    *reinterpret_cast<bfrag*>(xb + faddr(b, ti, w, j, s0, pxl + 16 * kh0)) = o0;
    *reinterpret_cast<bfrag*>(xb + faddr(b, ti, w, j, s1, pxl + 16 * kh1)) = o1;
  }
}

// ---------------- prep: pack W into MFMA fragment order ----------------
__global__ __launch_bounds__(256) void k_wpack(const float* __restrict__ w,
                                               unsigned short* __restrict__ wp) {
  const int g = blockIdx.x * 256 + threadIdx.x;
  if (g >= 216 * 64) return;
  const int frag = g >> 6, lane = g & 63;
  const int mb = frag / 24, r = frag % 24, s = r >> 2, i = r & 3;
  const int row = mb * 64 + i * 16 + (lane & 15);
  const int col = s * 32 + (lane >> 4) * 8;
  const float* src = w + (size_t)row * CC + col;
  float4 f0 = *reinterpret_cast<const float4*>(src);
  float4 f1 = *reinterpret_cast<const float4*>(src + 4);
  us4 o0, o1;
  o0[0] = f2bf(f0.x); o0[1] = f2bf(f0.y); o0[2] = f2bf(f0.z); o0[3] = f2bf(f0.w);
  o1[0] = f2bf(f1.x); o1[1] = f2bf(f1.y); o1[2] = f2bf(f1.z); o1[3] = f2bf(f1.w);
  *reinterpret_cast<us4*>(wp + (size_t)g * 8) = o0;
  *reinterpret_cast<us4*>(wp + (size_t)g * 8 + 4) = o1;
}

// ---------------- qkv GEMM: zero-LDS, zero-barrier ----------------
// Block = 256 px (8 waves, 2 tiles of 128), B-frags held in registers across
// all 9 mb; A from packed Wp (wave-contiguous). Grid 512 -> 2 blocks/CU, one
// generation, no tail.
__global__ __launch_bounds__(512, 4) void k_gemm_qkv(const unsigned short* __restrict__ Wp,
                                                     const unsigned short* __restrict__ XB,
                                                     unsigned short* __restrict__ Y) {
  const int nb = blockIdx.x;  // 64 double-tiles of 256 px
  const int b  = blockIdx.y;
  const int tid = threadIdx.x;
  const int wave = tid >> 6, lane = tid & 63;
  const int lrow = lane & 15, lr4 = (lane >> 4) * 4;
  const int tile = nb * 2 + (wave >> 2), w = wave & 3;

  bfrag bq[2][6];
#pragma unroll
  for (int j = 0; j < 2; ++j)
#pragma unroll
    for (int s = 0; s < 6; ++s)
      bq[j][s] = *reinterpret_cast<const bfrag*>(XB + faddr(b, tile, w, j, s, lane));

  const f32x4 z4 = {0.f, 0.f, 0.f, 0.f};
#pragma unroll 1
  for (int mb = 0; mb < 9; ++mb) {
    const unsigned short* Wb = Wp + (size_t)mb * 24 * 512;
    f32x4 acc[4][2];
#pragma unroll
    for (int i = 0; i < 4; ++i) { acc[i][0] = z4; acc[i][1] = z4; }
#pragma unroll
    for (int s = 0; s < 6; ++s) {
      bfrag af[4];
#pragma unroll
      for (int i = 0; i < 4; ++i)
        af[i] = *reinterpret_cast<const bfrag*>(Wb + ((s * 4 + i) * 64 + lane) * 8);
#pragma unroll
      for (int i = 0; i < 4; ++i) {
        acc[i][0] = MFMA16(bq[0][s], af[i], acc[i][0]);  // D[px][ch]
        acc[i][1] = MFMA16(bq[1][s], af[i], acc[i][1]);
      }
    }
    unsigned short* Yb = Y + ((size_t)b * C3 + mb * 64) * HW + tile * 128 + w * 32;
#pragma unroll
    for (int i = 0; i < 4; ++i) {
      unsigned short* rp = Yb + (size_t)(i * 16 + lrow) * HW;
#pragma unroll
      for (int j = 0; j < 2; ++j) {
        uint2 pk;
        pk.x = (unsigned int)f2bf(acc[i][j][0]) | ((unsigned int)f2bf(acc[i][j][1]) << 16);
        pk.y = (unsigned int)f2bf(acc[i][j][2]) | ((unsigned int)f2bf(acc[i][j][3]) << 16);
        *reinterpret_cast<uint2*>(rp + j * 16 + lr4) = pk;
      }
    }
  }
}

// ---------------- depthwise 3x3 SAME on q,k channels only (R8-proven) ----------------
__global__ __launch_bounds__(256) void k_dwconv(const unsigned short* __restrict__ in,
                                                const float* __restrict__ wd,
                                                unsigned short* __restrict__ outb) {
  const int strip = blockIdx.x;
  const int ch = blockIdx.y;
  const int b = blockIdx.z;
  const int t = threadIdx.x;
  const unsigned short* ip = in + ((size_t)b * C3 + ch) * HW;
  const float* w = wd + ch * 9;
  const int p = strip * 2048 + t * 8;
  const int y = p >> 7, x0 = p & 127;
  float acc[8] = {0.f, 0.f, 0.f, 0.f, 0.f, 0.f, 0.f, 0.f};
#pragma unroll
  for (int dy = 0; dy < 3; ++dy) {
    int yy = y + dy - 1;
    if (yy < 0 || yy > 127) continue;
    const unsigned short* row = ip + yy * 128;
    bfrag v = *reinterpret_cast<const bfrag*>(row + x0);
    float c[8];
#pragma unroll
    for (int e = 0; e < 8; ++e) c[e] = bf2f_s(v[e]);
    float left  = (x0 > 0)   ? bf2f(row[x0 - 1]) : 0.f;
    float right = (x0 < 120) ? bf2f(row[x0 + 8]) : 0.f;
    float wl = w[dy * 3 + 0], wc = w[dy * 3 + 1], wr = w[dy * 3 + 2];
    acc[0] += wl * left + wc * c[0] + wr * c[1];
#pragma unroll
    for (int e = 1; e < 7; ++e) acc[e] += wl * c[e - 1] + wc * c[e] + wr * c[e + 1];
    acc[7] += wl * c[6] + wc * c[7] + wr * right;
  }
  unsigned short* op = outb + ((size_t)b * 384 + ch) * HW + p;
  bfrag o;
#pragma unroll
  for (int e = 0; e < 8; ++e) o[e] = (short)f2bf(acc[e]);
  *reinterpret_cast<bfrag*>(op) = o;
}

// ---------------- gram from QKD [b][384][hw] (R1-proven) ----------------
__global__ __launch_bounds__(256) void k_gram(const unsigned short* __restrict__ Qd,
                                              float* __restrict__ S,
                                              float* __restrict__ ssq) {
  const int chunk = blockIdx.x;
  const int h = blockIdx.y, b = blockIdx.z;
  const int tid = threadIdx.x, wave = tid >> 6, lane = tid & 63;
  const int lrow = lane & 15, lk8 = (lane >> 4) * 8;
  const unsigned short* qb = Qd + ((size_t)b * 384 + h * 24) * HW;
  const unsigned short* kb = qb + (size_t)192 * HW;
  const int p0 = chunk * 1024 + wave * 256;
  f32x4 acc[2][2];
  const f32x4 z4 = {0.f, 0.f, 0.f, 0.f};
#pragma unroll
  for (int i = 0; i < 2; ++i)
#pragma unroll
    for (int j = 0; j < 2; ++j) acc[i][j] = z4;
  float sq[2] = {0.f, 0.f}, sk[2] = {0.f, 0.f};
  for (int s = 0; s < 8; ++s) {
    const int pp = p0 + s * 32 + lk8;
    bfrag aq[2], bk[2];
#pragma unroll
    for (int i = 0; i < 2; ++i) {
      aq[i] = *reinterpret_cast<const bfrag*>(qb + (size_t)(i * 16 + lrow) * HW + pp);
      bk[i] = *reinterpret_cast<const bfrag*>(kb + (size_t)(i * 16 + lrow) * HW + pp);
    }
#pragma unroll
    for (int i = 0; i < 2; ++i) {
#pragma unroll
      for (int e = 0; e < 8; ++e) {
        float qv = bf2f_s(aq[i][e]); sq[i] += qv * qv;
        float kv = bf2f_s(bk[i][e]); sk[i] += kv * kv;
      }
    }
#pragma unroll
    for (int i = 0; i < 2; ++i)
#pragma unroll
      for (int j = 0; j < 2; ++j) acc[i][j] = MFMA16(aq[i], bk[j], acc[i][j]);
  }
  float* Sb = S + (size_t)(b * 8 + h) * 1024;
  const int lr4 = (lane >> 4) * 4;
#pragma unroll
  for (int i = 0; i < 2; ++i)
#pragma unroll
    for (int j = 0; j < 2; ++j)
#pragma unroll
      for (int r = 0; r < 4; ++r)
        atomicAdd(&Sb[(i * 16 + lr4 + r) * 32 + j * 16 + lrow], acc[i][j][r]);
#pragma unroll
  for (int i = 0; i < 2; ++i) {
    float v = sq[i];
    v += __shfl_xor(v, 16); v += __shfl_xor(v, 32);
    float wv = sk[i];
    wv += __shfl_xor(wv, 16); wv += __shfl_xor(wv, 32);
    const int c = i * 16 + lrow;
    if ((lane >> 4) == 0 && c < 24) {
      atomicAdd(&ssq[b * 384 + h * 24 + c], v);
      atomicAdd(&ssq[b * 384 + 192 + h * 24 + c], wv);
    }
  }
}

// ---------------- fused dwconv(v) + transpose -> VT in FRAG order ----------------
__global__ __launch_bounds__(256) void k_dwvt(const unsigned short* __restrict__ QKV,
                                              const float* __restrict__ wd,
                                              unsigned short* __restrict__ VTo) {
  __shared__ unsigned short tile[64 * 72];
  const int pb = blockIdx.x * 64, cb = blockIdx.y * 64, b = blockIdx.z;
  const int t = threadIdx.x;
  const int y = pb >> 7;
  const int xs = pb & 127;
  {
    const int cl = t >> 2, ps = (t & 3) * 16;
    const int gc = 384 + cb + cl;
    const unsigned short* ip = QKV + ((size_t)b * C3 + gc) * HW;
    const float* w = wd + gc * 9;
    const int x0 = xs + ps;
    float acc[16];
#pragma unroll
    for (int e = 0; e < 16; ++e) acc[e] = 0.f;
#pragma unroll
    for (int dy = 0; dy < 3; ++dy) {
      int yy = y + dy - 1;
      if (yy < 0 || yy > 127) continue;
      const unsigned short* row = ip + yy * 128;
      bfrag v0 = *reinterpret_cast<const bfrag*>(row + x0);
      bfrag v1 = *reinterpret_cast<const bfrag*>(row + x0 + 8);
      float c[16];
#pragma unroll
      for (int e = 0; e < 8; ++e) { c[e] = bf2f_s(v0[e]); c[8 + e] = bf2f_s(v1[e]); }
      float left  = (x0 > 0)   ? bf2f(row[x0 - 1])  : 0.f;
      float right = (x0 < 112) ? bf2f(row[x0 + 16]) : 0.f;
      float wl = w[dy * 3 + 0], wc = w[dy * 3 + 1], wr = w[dy * 3 + 2];
      acc[0] += wl * left + wc * c[0] + wr * c[1];
#pragma unroll
      for (int e = 1; e < 15; ++e) acc[e] += wl * c[e - 1] + wc * c[e] + wr * c[e + 1];
      acc[15] += wl * c[14] + wc * c[15] + wr * right;
    }
    bfrag o0, o1;
#pragma unroll
    for (int e = 0; e < 8; ++e) { o0[e] = (short)f2bf(acc[e]); o1[e] = (short)f2bf(acc[8 + e]); }
    *reinterpret_cast<bfrag*>(&tile[cl * 72 + ps]) = o0;
    *reinterpret_cast<bfrag*>(&tile[cl * 72 + ps + 8]) = o1;
  }
  __syncthreads();
  {
    const int pl = t >> 2, cs = (t & 3) * 16;
    bfrag o0, o1;
#pragma unroll
    for (int e = 0; e < 8; ++e) o0[e] = (short)tile[(cs + e) * 72 + pl];
#pragma unroll
    for (int e = 0; e < 8; ++e) o1[e] = (short)tile[(cs + 8 + e) * 72 + pl];
    const int P = pb + pl, ch0 = cb + cs;
    const int ti = P >> 7, pit = P & 127;
    const int w = pit >> 5, j = (pit >> 4) & 1, pxl = pit & 15;
    const int s0 = ch0 >> 5, kh0 = (ch0 >> 3) & 3;
    const int ch1 = ch0 + 8, s1 = ch1 >> 5, kh1 = (ch1 >> 3) & 3;
    *reinterpret_cast<bfrag*>(VTo + faddr(b, ti, w, j, s0, pxl + 16 * kh0)) = o0;
    *reinterpret_cast<bfrag*>(VTo + faddr(b, ti, w, j, s1, pxl + 16 * kh1)) = o1;
  }
}

// ---------------- softmax + M = wproj @ blockdiag(attn), written PACKED ----------------
__global__ __launch_bounds__(64) void k_attn(const float* __restrict__ S,
                                             const float* __restrict__ ssq,
                                             const float* __restrict__ wproj,
                                             const float* __restrict__ temp,
                                             unsigned short* __restrict__ Mp) {
  const int h = blockIdx.x, b = blockIdx.y;
  __shared__ float A[24][25];
  __shared__ float nq[24], nk[24];
  const float* Sb = S + (size_t)(b * 8 + h) * 1024;
  const float* sq = ssq + b * 384 + h * 24;
  const float* sk = ssq + b * 384 + 192 + h * 24;
  const int t = threadIdx.x;
  if (t < 24) {
    nq[t] = fmaxf(sqrtf(sq[t]), 1e-12f);
    nk[t] = fmaxf(sqrtf(sk[t]), 1e-12f);
  }
  __syncthreads();
  if (t < 24) {
    const float tp = temp[h];
    float row[24];
    float mx = -1e30f;
#pragma unroll
    for (int d = 0; d < 24; ++d) {
      row[d] = Sb[t * 32 + d] / (nq[t] * nk[d]) * tp;
      mx = fmaxf(mx, row[d]);
    }
    float s = 0.f;
#pragma unroll
    for (int d = 0; d < 24; ++d) { row[d] = __expf(row[d] - mx); s += row[d]; }
    const float inv = 1.f / s;
#pragma unroll
    for (int d = 0; d < 24; ++d) A[t][d] = row[d] * inv;
  }
  __syncthreads();
  for (int idx = t; idx < 192 * 24; idx += 64) {
    const int o = idx / 24, dd = idx % 24;
    const float* wrow = wproj + o * 192 + h * 24;
    float a = 0.f;
#pragma unroll
    for (int cc = 0; cc < 24; ++cc) a += wrow[cc] * A[cc][dd];
    const int c = h * 24 + dd;
    const int mb = o >> 6, i = (o >> 4) & 3, lr = o & 15;
    const int s = c >> 5, hi = (c >> 3) & 3, e = c & 7;
    const int off = ((mb * 24 + s * 4 + i) * 64 + hi * 16 + lr) * 8 + e;
    Mp[(size_t)b * CC * CC + off] = f2bf(a);
  }
}

// ---------------- out GEMM: zero-LDS, zero-barrier (frag-order VT) ----------------
__global__ __launch_bounds__(512, 4) void k_gemm_out(const unsigned short* __restrict__ Mp,
                                                     const unsigned short* __restrict__ VB,
                                                     float* __restrict__ out) {
  const int nb = blockIdx.x;  // 64 double-tiles of 256 px
  const int b  = blockIdx.y;
  const int tid = threadIdx.x;
  const int wave = tid >> 6, lane = tid & 63;
  const int lrow = lane & 15, lr4 = (lane >> 4) * 4;
  const int tile = nb * 2 + (wave >> 2), w = wave & 3;

  bfrag bq[2][6];
#pragma unroll
  for (int j = 0; j < 2; ++j)
#pragma unroll
    for (int s = 0; s < 6; ++s)
      bq[j][s] = *reinterpret_cast<const bfrag*>(VB + faddr(b, tile, w, j, s, lane));

  const f32x4 z4 = {0.f, 0.f, 0.f, 0.f};
#pragma unroll 1
  for (int mb = 0; mb < 3; ++mb) {
    const unsigned short* Mb = Mp + (size_t)b * CC * CC + (size_t)mb * 24 * 512;
    f32x4 acc[4][2];
#pragma unroll
    for (int i = 0; i < 4; ++i) { acc[i][0] = z4; acc[i][1] = z4; }
#pragma unroll
    for (int s = 0; s < 6; ++s) {
      bfrag af[4];
#pragma unroll
      for (int i = 0; i < 4; ++i)
        af[i] = *reinterpret_cast<const bfrag*>(Mb + ((s * 4 + i) * 64 + lane) * 8);
#pragma unroll
      for (int i = 0; i < 4; ++i) {
        acc[i][0] = MFMA16(bq[0][s], af[i], acc[i][0]);  // D[px][ch]
        acc[i][1] = MFMA16(bq[1][s], af[i], acc[i][1]);
      }
    }
    float* Ob = out + ((size_t)b * CC + mb * 64) * HW + tile * 128 + w * 32;
#pragma unroll
    for (int i = 0; i < 4; ++i) {
      float* rp = Ob + (size_t)(i * 16 + lrow) * HW;
#pragma unroll
      for (int j = 0; j < 2; ++j)
        *reinterpret_cast<f32x4*>(rp + j * 16 + lr4) = acc[i][j];
    }
  }
}

extern "C" void kernel_launch(void* const* d_in, const int* in_sizes, int n_in,
                              void* d_out, int out_size, void* d_ws, size_t ws_size,
                              hipStream_t stream) {
  const float* x      = (const float*)d_in[0];
  const float* w_qkv  = (const float*)d_in[1];
  const float* w_dw   = (const float*)d_in[2];
  const float* w_proj = (const float*)d_in[3];
  const float* temp   = (const float*)d_in[4];
  float* out = (float*)d_out;
  char* ws = (char*)d_ws;

  unsigned short* XB   = (unsigned short*)(ws + OFF_XT);
  unsigned short* VB   = (unsigned short*)(ws + OFF_XT);  // reuse: XB dead after qkv GEMM
  unsigned short* WP   = (unsigned short*)(ws + OFF_WQ);
  unsigned short* QKV  = (unsigned short*)(ws + OFF_QKV);
  unsigned short* QKD  = (unsigned short*)(ws + OFF_QKD);
  float* S   = (float*)(ws + OFF_S);
  float* SSQ = (float*)(ws + OFF_SSQ);
  unsigned short* MP  = (unsigned short*)(ws + OFF_M);

  hipMemsetAsync(ws + OFF_S, 0, SZ_S + SZ_SSQ, stream);
  k_wpack<<<54, 256, 0, stream>>>(w_qkv, WP);
  k_xt<<<dim3(HW / 64, CC / 64, NB), 256, 0, stream>>>(x, XB);
  k_gemm_qkv<<<dim3(64, NB), 512, 0, stream>>>(WP, XB, QKV);
  k_dwconv<<<dim3(8, 384, NB), 256, 0, stream>>>(QKV, w_dw, QKD);
  k_dwvt<<<dim3(HW / 64, 3, NB), 256, 0, stream>>>(QKV, w_dw, VB);
  k_gram<<<dim3(16, NH, NB), 256, 0, stream>>>(QKD, S, SSQ);
  k_attn<<<dim3(NH, NB), 64, 0, stream>>>(S, SSQ, w_proj, temp, MP);
  k_gemm_out<<<dim3(64, NB), 512, 0, stream>>>(MP, VB, out);
}

// Round 14
// 315.915 us; speedup vs baseline: 1.1189x; 1.0195x over previous
//
#include <hip/hip_runtime.h>

#define HW 16384
#define HWP 16416   // padded channel stride (+32 px = +64B): breaks 32KB power-of-2 L2-channel camping
#define CC 192
#define C3 576
#define NB 8
#define NH 8

typedef __attribute__((ext_vector_type(8))) short bfrag;
typedef __attribute__((ext_vector_type(4))) float f32x4;
typedef __attribute__((ext_vector_type(4))) unsigned short us4;

#define MFMA16(a, b, c) __builtin_amdgcn_mfma_f32_16x16x32_bf16(a, b, c, 0, 0, 0)

__device__ __forceinline__ unsigned short f2bf(float f) {
  unsigned int u = __float_as_uint(f);
  u += 0x7fffu + ((u >> 16) & 1u);
  return (unsigned short)(u >> 16);
}
__device__ __forceinline__ float bf2f(unsigned short s) {
  return __uint_as_float(((unsigned int)s) << 16);
}
__device__ __forceinline__ float bf2f_s(short s) {
  return __uint_as_float(((unsigned int)(unsigned short)s) << 16);
}

// fragment-order address (elements) for B operands:
// px_in_tile = w*32 + j*16 + (lane&15); ch = s*32 + ((lane>>4)&3)*8 + e
__device__ __forceinline__ size_t faddr(int b, int tile, int w, int j, int s, int lane) {
  return ((((((size_t)b * 128 + tile) * 4 + w) * 2 + j) * 6 + s) * 512 + (size_t)lane * 8);
}

// ---------------- workspace layout (bytes) ----------------
#define OFF_XT   0ull
#define SZ_XT    ((size_t)NB * HW * CC * 2)      // x bf16 in FRAG order; later reused as VT (frag order)
#define OFF_WQ   (OFF_XT + SZ_XT)
#define SZ_WQ    ((size_t)C3 * CC * 2)           // W packed into MFMA frag order
#define OFF_QKV  (OFF_WQ + SZ_WQ)
#define SZ_QKV   ((size_t)NB * C3 * HWP * 2)     // qkv (pre-dw) bf16 [b][576][HWP]
#define OFF_QKD  (OFF_QKV + SZ_QKV)
#define SZ_QKD   ((size_t)NB * 384 * HWP * 2)    // post-dw q,k only [b][384][HWP]
#define OFF_S    (OFF_QKD + SZ_QKD)
#define SZ_S     ((size_t)NB * NH * 32 * 32 * 4) // gram fp32 [b][h][32][32]
#define OFF_SSQ  (OFF_S + SZ_S)
#define SZ_SSQ   ((size_t)NB * 384 * 4)          // sumsq fp32 [b][q:192 | k:192]
#define OFF_M    (OFF_SSQ + SZ_SSQ)
#define SZ_M     ((size_t)NB * CC * CC * 2)      // fused proj*attn, packed frag order

// ---------------- prep: x -> bf16 FRAG-ORDER [b][tile][w][j][s][lane][8] ----------------
__global__ __launch_bounds__(256) void k_xt(const float* __restrict__ x,
                                            unsigned short* __restrict__ xb) {
  __shared__ unsigned short tile[64 * 72];
  const int pb = blockIdx.x * 64;
  const int cb = blockIdx.y * 64;
  const int b  = blockIdx.z;
  const int t  = threadIdx.x;
  {
    const int cl = t >> 2, pl = (t & 3) * 16;
    const float* src = x + ((size_t)b * CC + cb + cl) * HW + pb + pl;
    bfrag v0, v1;
#pragma unroll
    for (int q4 = 0; q4 < 2; ++q4) {
      float4 f = *reinterpret_cast<const float4*>(src + q4 * 4);
      v0[q4 * 4 + 0] = (short)f2bf(f.x); v0[q4 * 4 + 1] = (short)f2bf(f.y);
      v0[q4 * 4 + 2] = (short)f2bf(f.z); v0[q4 * 4 + 3] = (short)f2bf(f.w);
    }
#pragma unroll
    for (int q4 = 0; q4 < 2; ++q4) {
      float4 f = *reinterpret_cast<const float4*>(src + 8 + q4 * 4);
      v1[q4 * 4 + 0] = (short)f2bf(f.x); v1[q4 * 4 + 1] = (short)f2bf(f.y);
      v1[q4 * 4 + 2] = (short)f2bf(f.z); v1[q4 * 4 + 3] = (short)f2bf(f.w);
    }
    *reinterpret_cast<bfrag*>(&tile[cl * 72 + pl]) = v0;
    *reinterpret_cast<bfrag*>(&tile[cl * 72 + pl + 8]) = v1;
  }
  __syncthreads();
  {
    const int pl = t >> 2, cl = (t & 3) * 16;
    bfrag o0, o1;
#pragma unroll
    for (int e = 0; e < 8; ++e) o0[e] = (short)tile[(cl + e) * 72 + pl];
#pragma unroll
    for (int e = 0; e < 8; ++e) o1[e] = (short)tile[(cl + 8 + e) * 72 + pl];
    const int P = pb + pl, ch0 = cb + cl;
    const int ti = P >> 7, pit = P & 127;
    const int w = pit >> 5, j = (pit >> 4) & 1, pxl = pit & 15;
    const int s0 = ch0 >> 5, kh0 = (ch0 >> 3) & 3;
    const int ch1 = ch0 + 8, s1 = ch1 >> 5, kh1 = (ch1 >> 3) & 3;
    *reinterpret_cast<bfrag*>(xb + faddr(b, ti, w, j, s0, pxl + 16 * kh0)) = o0;
    *reinterpret_cast<bfrag*>(xb + faddr(b, ti, w, j, s1, pxl + 16 * kh1)) = o1;
  }
}

// ---------------- prep: pack W into MFMA fragment order ----------------
__global__ __launch_bounds__(256) void k_wpack(const float* __restrict__ w,
                                               unsigned short* __restrict__ wp) {
  const int g = blockIdx.x * 256 + threadIdx.x;
  if (g >= 216 * 64) return;
  const int frag = g >> 6, lane = g & 63;
  const int mb = frag / 24, r = frag % 24, s = r >> 2, i = r & 3;
  const int row = mb * 64 + i * 16 + (lane & 15);
  const int col = s * 32 + (lane >> 4) * 8;
  const float* src = w + (size_t)row * CC + col;
  float4 f0 = *reinterpret_cast<const float4*>(src);
  float4 f1 = *reinterpret_cast<const float4*>(src + 4);
  us4 o0, o1;
  o0[0] = f2bf(f0.x); o0[1] = f2bf(f0.y); o0[2] = f2bf(f0.z); o0[3] = f2bf(f0.w);
  o1[0] = f2bf(f1.x); o1[1] = f2bf(f1.y); o1[2] = f2bf(f1.z); o1[3] = f2bf(f1.w);
  *reinterpret_cast<us4*>(wp + (size_t)g * 8) = o0;
  *reinterpret_cast<us4*>(wp + (size_t)g * 8 + 4) = o1;
}

// ---------------- qkv GEMM: zero-LDS, zero-barrier, PADDED output stride ----------------
__global__ __launch_bounds__(512, 4) void k_gemm_qkv(const unsigned short* __restrict__ Wp,
                                                     const unsigned short* __restrict__ XB,
                                                     unsigned short* __restrict__ Y) {
  const int nb = blockIdx.x;  // 64 double-tiles of 256 px
  const int b  = blockIdx.y;
  const int tid = threadIdx.x;
  const int wave = tid >> 6, lane = tid & 63;
  const int lrow = lane & 15, lr4 = (lane >> 4) * 4;
  const int tile = nb * 2 + (wave >> 2), w = wave & 3;

  bfrag bq[2][6];
#pragma unroll
  for (int j = 0; j < 2; ++j)
#pragma unroll
    for (int s = 0; s < 6; ++s)
      bq[j][s] = *reinterpret_cast<const bfrag*>(XB + faddr(b, tile, w, j, s, lane));

  const f32x4 z4 = {0.f, 0.f, 0.f, 0.f};
#pragma unroll 1
  for (int mb = 0; mb < 9; ++mb) {
    const unsigned short* Wb = Wp + (size_t)mb * 24 * 512;
    f32x4 acc[4][2];
#pragma unroll
    for (int i = 0; i < 4; ++i) { acc[i][0] = z4; acc[i][1] = z4; }
#pragma unroll
    for (int s = 0; s < 6; ++s) {
      bfrag af[4];
#pragma unroll
      for (int i = 0; i < 4; ++i)
        af[i] = *reinterpret_cast<const bfrag*>(Wb + ((s * 4 + i) * 64 + lane) * 8);
#pragma unroll
      for (int i = 0; i < 4; ++i) {
        acc[i][0] = MFMA16(bq[0][s], af[i], acc[i][0]);  // D[px][ch]
        acc[i][1] = MFMA16(bq[1][s], af[i], acc[i][1]);
      }
    }
    unsigned short* Yb = Y + ((size_t)b * C3 + mb * 64) * HWP + tile * 128 + w * 32;
#pragma unroll
    for (int i = 0; i < 4; ++i) {
      unsigned short* rp = Yb + (size_t)(i * 16 + lrow) * HWP;
#pragma unroll
      for (int j = 0; j < 2; ++j) {
        uint2 pk;
        pk.x = (unsigned int)f2bf(acc[i][j][0]) | ((unsigned int)f2bf(acc[i][j][1]) << 16);
        pk.y = (unsigned int)f2bf(acc[i][j][2]) | ((unsigned int)f2bf(acc[i][j][3]) << 16);
        *reinterpret_cast<uint2*>(rp + j * 16 + lr4) = pk;
      }
    }
  }
}

// ---------------- depthwise 3x3 SAME on q,k channels only (padded strides) ----------------
__global__ __launch_bounds__(256) void k_dwconv(const unsigned short* __restrict__ in,
                                                const float* __restrict__ wd,
                                                unsigned short* __restrict__ outb) {
  const int strip = blockIdx.x;
  const int ch = blockIdx.y;
  const int b = blockIdx.z;
  const int t = threadIdx.x;
  const unsigned short* ip = in + ((size_t)b * C3 + ch) * HWP;
  const float* w = wd + ch * 9;
  const int p = strip * 2048 + t * 8;
  const int y = p >> 7, x0 = p & 127;
  float acc[8] = {0.f, 0.f, 0.f, 0.f, 0.f, 0.f, 0.f, 0.f};
#pragma unroll
  for (int dy = 0; dy < 3; ++dy) {
    int yy = y + dy - 1;
    if (yy < 0 || yy > 127) continue;
    const unsigned short* row = ip + yy * 128;
    bfrag v = *reinterpret_cast<const bfrag*>(row + x0);
    float c[8];
#pragma unroll
    for (int e = 0; e < 8; ++e) c[e] = bf2f_s(v[e]);
    float left  = (x0 > 0)   ? bf2f(row[x0 - 1]) : 0.f;
    float right = (x0 < 120) ? bf2f(row[x0 + 8]) : 0.f;
    float wl = w[dy * 3 + 0], wc = w[dy * 3 + 1], wr = w[dy * 3 + 2];
    acc[0] += wl * left + wc * c[0] + wr * c[1];
#pragma unroll
    for (int e = 1; e < 7; ++e) acc[e] += wl * c[e - 1] + wc * c[e] + wr * c[e + 1];
    acc[7] += wl * c[6] + wc * c[7] + wr * right;
  }
  unsigned short* op = outb + ((size_t)b * 384 + ch) * HWP + p;
  bfrag o;
#pragma unroll
  for (int e = 0; e < 8; ++e) o[e] = (short)f2bf(acc[e]);
  *reinterpret_cast<bfrag*>(op) = o;
}

// ---------------- gram from QKD [b][384][HWP] ----------------
__global__ __launch_bounds__(256) void k_gram(const unsigned short* __restrict__ Qd,
                                              float* __restrict__ S,
                                              float* __restrict__ ssq) {
  const int chunk = blockIdx.x;
  const int h = blockIdx.y, b = blockIdx.z;
  const int tid = threadIdx.x, wave = tid >> 6, lane = tid & 63;
  const int lrow = lane & 15, lk8 = (lane >> 4) * 8;
  const unsigned short* qb = Qd + ((size_t)b * 384 + h * 24) * HWP;
  const unsigned short* kb = qb + (size_t)192 * HWP;
  const int p0 = chunk * 1024 + wave * 256;
  f32x4 acc[2][2];
  const f32x4 z4 = {0.f, 0.f, 0.f, 0.f};
#pragma unroll
  for (int i = 0; i < 2; ++i)
#pragma unroll
    for (int j = 0; j < 2; ++j) acc[i][j] = z4;
  float sq[2] = {0.f, 0.f}, sk[2] = {0.f, 0.f};
  for (int s = 0; s < 8; ++s) {
    const int pp = p0 + s * 32 + lk8;
    bfrag aq[2], bk[2];
#pragma unroll
    for (int i = 0; i < 2; ++i) {
      aq[i] = *reinterpret_cast<const bfrag*>(qb + (size_t)(i * 16 + lrow) * HWP + pp);
      bk[i] = *reinterpret_cast<const bfrag*>(kb + (size_t)(i * 16 + lrow) * HWP + pp);
    }
#pragma unroll
    for (int i = 0; i < 2; ++i) {
#pragma unroll
      for (int e = 0; e < 8; ++e) {
        float qv = bf2f_s(aq[i][e]); sq[i] += qv * qv;
        float kv = bf2f_s(bk[i][e]); sk[i] += kv * kv;
      }
    }
#pragma unroll
    for (int i = 0; i < 2; ++i)
#pragma unroll
      for (int j = 0; j < 2; ++j) acc[i][j] = MFMA16(aq[i], bk[j], acc[i][j]);
  }
  float* Sb = S + (size_t)(b * 8 + h) * 1024;
  const int lr4 = (lane >> 4) * 4;
#pragma unroll
  for (int i = 0; i < 2; ++i)
#pragma unroll
    for (int j = 0; j < 2; ++j)
#pragma unroll
      for (int r = 0; r < 4; ++r)
        atomicAdd(&Sb[(i * 16 + lr4 + r) * 32 + j * 16 + lrow], acc[i][j][r]);
#pragma unroll
  for (int i = 0; i < 2; ++i) {
    float v = sq[i];
    v += __shfl_xor(v, 16); v += __shfl_xor(v, 32);
    float wv = sk[i];
    wv += __shfl_xor(wv, 16); wv += __shfl_xor(wv, 32);
    const int c = i * 16 + lrow;
    if ((lane >> 4) == 0 && c < 24) {
      atomicAdd(&ssq[b * 384 + h * 24 + c], v);
      atomicAdd(&ssq[b * 384 + 192 + h * 24 + c], wv);
    }
  }
}

// ---------------- fused dwconv(v) + transpose -> VT in FRAG order (padded input) ----------------
__global__ __launch_bounds__(256) void k_dwvt(const unsigned short* __restrict__ QKV,
                                              const float* __restrict__ wd,
                                              unsigned short* __restrict__ VTo) {
  __shared__ unsigned short tile[64 * 72];
  const int pb = blockIdx.x * 64, cb = blockIdx.y * 64, b = blockIdx.z;
  const int t = threadIdx.x;
  const int y = pb >> 7;
  const int xs = pb & 127;
  {
    const int cl = t >> 2, ps = (t & 3) * 16;
    const int gc = 384 + cb + cl;
    const unsigned short* ip = QKV + ((size_t)b * C3 + gc) * HWP;
    const float* w = wd + gc * 9;
    const int x0 = xs + ps;
    float acc[16];
#pragma unroll
    for (int e = 0; e < 16; ++e) acc[e] = 0.f;
#pragma unroll
    for (int dy = 0; dy < 3; ++dy) {
      int yy = y + dy - 1;
      if (yy < 0 || yy > 127) continue;
      const unsigned short* row = ip + yy * 128;
      bfrag v0 = *reinterpret_cast<const bfrag*>(row + x0);
      bfrag v1 = *reinterpret_cast<const bfrag*>(row + x0 + 8);
      float c[16];
#pragma unroll
      for (int e = 0; e < 8; ++e) { c[e] = bf2f_s(v0[e]); c[8 + e] = bf2f_s(v1[e]); }
      float left  = (x0 > 0)   ? bf2f(row[x0 - 1])  : 0.f;
      float right = (x0 < 112) ? bf2f(row[x0 + 16]) : 0.f;
      float wl = w[dy * 3 + 0], wc = w[dy * 3 + 1], wr = w[dy * 3 + 2];
      acc[0] += wl * left + wc * c[0] + wr * c[1];
#pragma unroll
      for (int e = 1; e < 15; ++e) acc[e] += wl * c[e - 1] + wc * c[e] + wr * c[e + 1];
      acc[15] += wl * c[14] + wc * c[15] + wr * right;
    }
    bfrag o0, o1;
#pragma unroll
    for (int e = 0; e < 8; ++e) { o0[e] = (short)f2bf(acc[e]); o1[e] = (short)f2bf(acc[8 + e]); }
    *reinterpret_cast<bfrag*>(&tile[cl * 72 + ps]) = o0;
    *reinterpret_cast<bfrag*>(&tile[cl * 72 + ps + 8]) = o1;
  }
  __syncthreads();
  {
    const int pl = t >> 2, cs = (t & 3) * 16;
    bfrag o0, o1;
#pragma unroll
    for (int e = 0; e < 8; ++e) o0[e] = (short)tile[(cs + e) * 72 + pl];
#pragma unroll
    for (int e = 0; e < 8; ++e) o1[e] = (short)tile[(cs + 8 + e) * 72 + pl];
    const int P = pb + pl, ch0 = cb + cs;
    const int ti = P >> 7, pit = P & 127;
    const int w = pit >> 5, j = (pit >> 4) & 1, pxl = pit & 15;
    const int s0 = ch0 >> 5, kh0 = (ch0 >> 3) & 3;
    const int ch1 = ch0 + 8, s1 = ch1 >> 5, kh1 = (ch1 >> 3) & 3;
    *reinterpret_cast<bfrag*>(VTo + faddr(b, ti, w, j, s0, pxl + 16 * kh0)) = o0;
    *reinterpret_cast<bfrag*>(VTo + faddr(b, ti, w, j, s1, pxl + 16 * kh1)) = o1;
  }
}

// ---------------- softmax + M = wproj @ blockdiag(attn), written PACKED ----------------
__global__ __launch_bounds__(64) void k_attn(const float* __restrict__ S,
                                             const float* __restrict__ ssq,
                                             const float* __restrict__ wproj,
                                             const float* __restrict__ temp,
                                             unsigned short* __restrict__ Mp) {
  const int h = blockIdx.x, b = blockIdx.y;
  __shared__ float A[24][25];
  __shared__ float nq[24], nk[24];
  const float* Sb = S + (size_t)(b * 8 + h) * 1024;
  const float* sq = ssq + b * 384 + h * 24;
  const float* sk = ssq + b * 384 + 192 + h * 24;
  const int t = threadIdx.x;
  if (t < 24) {
    nq[t] = fmaxf(sqrtf(sq[t]), 1e-12f);
    nk[t] = fmaxf(sqrtf(sk[t]), 1e-12f);
  }
  __syncthreads();
  if (t < 24) {
    const float tp = temp[h];
    float row[24];
    float mx = -1e30f;
#pragma unroll
    for (int d = 0; d < 24; ++d) {
      row[d] = Sb[t * 32 + d] / (nq[t] * nk[d]) * tp;
      mx = fmaxf(mx, row[d]);
    }
    float s = 0.f;
#pragma unroll
    for (int d = 0; d < 24; ++d) { row[d] = __expf(row[d] - mx); s += row[d]; }
    const float inv = 1.f / s;
#pragma unroll
    for (int d = 0; d < 24; ++d) A[t][d] = row[d] * inv;
  }
  __syncthreads();
  for (int idx = t; idx < 192 * 24; idx += 64) {
    const int o = idx / 24, dd = idx % 24;
    const float* wrow = wproj + o * 192 + h * 24;
    float a = 0.f;
#pragma unroll
    for (int cc = 0; cc < 24; ++cc) a += wrow[cc] * A[cc][dd];
    const int c = h * 24 + dd;
    const int mb = o >> 6, i = (o >> 4) & 3, lr = o & 15;
    const int s = c >> 5, hi = (c >> 3) & 3, e = c & 7;
    const int off = ((mb * 24 + s * 4 + i) * 64 + hi * 16 + lr) * 8 + e;
    Mp[(size_t)b * CC * CC + off] = f2bf(a);
  }
}

// ---------------- out GEMM: zero-LDS, zero-barrier (frag-order VT) ----------------
__global__ __launch_bounds__(512, 4) void k_gemm_out(const unsigned short* __restrict__ Mp,
                                                     const unsigned short* __restrict__ VB,
                                                     float* __restrict__ out) {
  const int nb = blockIdx.x;  // 64 double-tiles of 256 px
  const int b  = blockIdx.y;
  const int tid = threadIdx.x;
  const int wave = tid >> 6, lane = tid & 63;
  const int lrow = lane & 15, lr4 = (lane >> 4) * 4;
  const int tile = nb * 2 + (wave >> 2), w = wave & 3;

  bfrag bq[2][6];
#pragma unroll
  for (int j = 0; j < 2; ++j)
#pragma unroll
    for (int s = 0; s < 6; ++s)
      bq[j][s] = *reinterpret_cast<const bfrag*>(VB + faddr(b, tile, w, j, s, lane));

  const f32x4 z4 = {0.f, 0.f, 0.f, 0.f};
#pragma unroll 1
  for (int mb = 0; mb < 3; ++mb) {
    const unsigned short* Mb = Mp + (size_t)b * CC * CC + (size_t)mb * 24 * 512;
    f32x4 acc[4][2];
#pragma unroll
    for (int i = 0; i < 4; ++i) { acc[i][0] = z4; acc[i][1] = z4; }
#pragma unroll
    for (int s = 0; s < 6; ++s) {
      bfrag af[4];
#pragma unroll
      for (int i = 0; i < 4; ++i)
        af[i] = *reinterpret_cast<const bfrag*>(Mb + ((s * 4 + i) * 64 + lane) * 8);
#pragma unroll
      for (int i = 0; i < 4; ++i) {
        acc[i][0] = MFMA16(bq[0][s], af[i], acc[i][0]);  // D[px][ch]
        acc[i][1] = MFMA16(bq[1][s], af[i], acc[i][1]);
      }
    }
    float* Ob = out + ((size_t)b * CC + mb * 64) * HW + tile * 128 + w * 32;
#pragma unroll
    for (int i = 0; i < 4; ++i) {
      float* rp = Ob + (size_t)(i * 16 + lrow) * HW;
#pragma unroll
      for (int j = 0; j < 2; ++j)
        *reinterpret_cast<f32x4*>(rp + j * 16 + lr4) = acc[i][j];
    }
  }
}

extern "C" void kernel_launch(void* const* d_in, const int* in_sizes, int n_in,
                              void* d_out, int out_size, void* d_ws, size_t ws_size,
                              hipStream_t stream) {
  const float* x      = (const float*)d_in[0];
  const float* w_qkv  = (const float*)d_in[1];
  const float* w_dw   = (const float*)d_in[2];
  const float* w_proj = (const float*)d_in[3];
  const float* temp   = (const float*)d_in[4];
  float* out = (float*)d_out;
  char* ws = (char*)d_ws;

  unsigned short* XB   = (unsigned short*)(ws + OFF_XT);
  unsigned short* VB   = (unsigned short*)(ws + OFF_XT);  // reuse: XB dead after qkv GEMM
  unsigned short* WP   = (unsigned short*)(ws + OFF_WQ);
  unsigned short* QKV  = (unsigned short*)(ws + OFF_QKV);
  unsigned short* QKD  = (unsigned short*)(ws + OFF_QKD);
  float* S   = (float*)(ws + OFF_S);
  float* SSQ = (float*)(ws + OFF_SSQ);
  unsigned short* MP  = (unsigned short*)(ws + OFF_M);

  hipMemsetAsync(ws + OFF_S, 0, SZ_S + SZ_SSQ, stream);
  k_wpack<<<54, 256, 0, stream>>>(w_qkv, WP);
  k_xt<<<dim3(HW / 64, CC / 64, NB), 256, 0, stream>>>(x, XB);
  k_gemm_qkv<<<dim3(64, NB), 512, 0, stream>>>(WP, XB, QKV);
  k_dwconv<<<dim3(8, 384, NB), 256, 0, stream>>>(QKV, w_dw, QKD);
  k_dwvt<<<dim3(HW / 64, 3, NB), 256, 0, stream>>>(QKV, w_dw, VB);
  k_gram<<<dim3(16, NH, NB), 256, 0, stream>>>(QKD, S, SSQ);
  k_attn<<<dim3(NH, NB), 64, 0, stream>>>(S, SSQ, w_proj, temp, MP);
  k_gemm_out<<<dim3(64, NB), 512, 0, stream>>>(MP, VB, out);
}

// Round 15
// 301.895 us; speedup vs baseline: 1.1709x; 1.0464x over previous
//
#include <hip/hip_runtime.h>

#define HW 16384
#define HWP 16416   // padded channel stride (+32 px = +64B): breaks 32KB power-of-2 L2-channel camping
#define CC 192
#define C3 576
#define NB 8
#define NH 8

typedef __attribute__((ext_vector_type(8))) short bfrag;
typedef __attribute__((ext_vector_type(4))) float f32x4;
typedef __attribute__((ext_vector_type(4))) unsigned short us4;

#define MFMA16(a, b, c) __builtin_amdgcn_mfma_f32_16x16x32_bf16(a, b, c, 0, 0, 0)

__device__ __forceinline__ unsigned short f2bf(float f) {
  unsigned int u = __float_as_uint(f);
  u += 0x7fffu + ((u >> 16) & 1u);
  return (unsigned short)(u >> 16);
}
__device__ __forceinline__ float bf2f(unsigned short s) {
  return __uint_as_float(((unsigned int)s) << 16);
}
__device__ __forceinline__ float bf2f_s(short s) {
  return __uint_as_float(((unsigned int)(unsigned short)s) << 16);
}
__device__ __forceinline__ unsigned int pk2(float lo, float hi) {
  return (unsigned int)f2bf(lo) | ((unsigned int)f2bf(hi) << 16);
}

// fragment-order address (elements) for B operands:
// frag (tile,w,j,s), lane = row + 16*khalf, 8 contiguous ch elements per lane
__device__ __forceinline__ size_t faddr(int b, int tile, int w, int j, int s, int lane) {
  return ((((((size_t)b * 128 + tile) * 4 + w) * 2 + j) * 6 + s) * 512 + (size_t)lane * 8);
}

// ---------------- workspace layout (bytes) ----------------
#define OFF_XT   0ull
#define SZ_XT    ((size_t)NB * HW * CC * 2)      // x bf16 in FRAG order; later reused as VT (frag order)
#define OFF_WQ   (OFF_XT + SZ_XT)
#define SZ_WQ    ((size_t)C3 * CC * 2)           // W packed into MFMA frag order
#define OFF_QKV  (OFF_WQ + SZ_WQ)
#define SZ_QKV   ((size_t)NB * C3 * HWP * 2)     // qkv (pre-dw) bf16 [b][576][HWP]
#define OFF_QKD  (OFF_QKV + SZ_QKV)
#define SZ_QKD   ((size_t)NB * 384 * HWP * 2)    // post-dw q,k only [b][384][HWP]
#define OFF_S    (OFF_QKD + SZ_QKD)
#define SZ_S     ((size_t)NB * NH * 32 * 32 * 4) // gram fp32 [b][h][32][32]
#define OFF_SSQ  (OFF_S + SZ_S)
#define SZ_SSQ   ((size_t)NB * 384 * 4)          // sumsq fp32 [b][q:192 | k:192]
#define OFF_M    (OFF_SSQ + SZ_SSQ)
#define SZ_M     ((size_t)NB * CC * CC * 2)      // fused proj*attn, packed frag order

// ---------------- prep: x -> bf16 FRAG-ORDER, px PERMUTED for full-line GEMM stores ----
// Within each 32-px window: j=(p32>>2)&1, row=((p32>>3)<<2)|(p32&3)
// -> GEMM lane (quadrant q) holds px q*8..q*8+7 contiguous across j=0,1.
__global__ __launch_bounds__(256) void k_xt(const float* __restrict__ x,
                                            unsigned short* __restrict__ xb) {
  __shared__ unsigned short tile[64 * 72];
  const int pb = blockIdx.x * 64;
  const int cb = blockIdx.y * 64;
  const int b  = blockIdx.z;
  const int t  = threadIdx.x;
  {
    const int cl = t >> 2, pl = (t & 3) * 16;
    const float* src = x + ((size_t)b * CC + cb + cl) * HW + pb + pl;
    bfrag v0, v1;
#pragma unroll
    for (int q4 = 0; q4 < 2; ++q4) {
      float4 f = *reinterpret_cast<const float4*>(src + q4 * 4);
      v0[q4 * 4 + 0] = (short)f2bf(f.x); v0[q4 * 4 + 1] = (short)f2bf(f.y);
      v0[q4 * 4 + 2] = (short)f2bf(f.z); v0[q4 * 4 + 3] = (short)f2bf(f.w);
    }
#pragma unroll
    for (int q4 = 0; q4 < 2; ++q4) {
      float4 f = *reinterpret_cast<const float4*>(src + 8 + q4 * 4);
      v1[q4 * 4 + 0] = (short)f2bf(f.x); v1[q4 * 4 + 1] = (short)f2bf(f.y);
      v1[q4 * 4 + 2] = (short)f2bf(f.z); v1[q4 * 4 + 3] = (short)f2bf(f.w);
    }
    *reinterpret_cast<bfrag*>(&tile[cl * 72 + pl]) = v0;
    *reinterpret_cast<bfrag*>(&tile[cl * 72 + pl + 8]) = v1;
  }
  __syncthreads();
  {
    const int pl = t >> 2, cl = (t & 3) * 16;
    bfrag o0, o1;
#pragma unroll
    for (int e = 0; e < 8; ++e) o0[e] = (short)tile[(cl + e) * 72 + pl];
#pragma unroll
    for (int e = 0; e < 8; ++e) o1[e] = (short)tile[(cl + 8 + e) * 72 + pl];
    const int P = pb + pl, ch0 = cb + cl;
    const int ti = P >> 7, pit = P & 127;
    const int w = pit >> 5, p32 = pit & 31;
    const int j = (p32 >> 2) & 1;
    const int r = ((p32 >> 3) << 2) | (p32 & 3);
    const int s0 = ch0 >> 5, kh0 = (ch0 >> 3) & 3;
    const int ch1 = ch0 + 8, s1 = ch1 >> 5, kh1 = (ch1 >> 3) & 3;
    *reinterpret_cast<bfrag*>(xb + faddr(b, ti, w, j, s0, r + 16 * kh0)) = o0;
    *reinterpret_cast<bfrag*>(xb + faddr(b, ti, w, j, s1, r + 16 * kh1)) = o1;
  }
}

// ---------------- prep: pack W into MFMA fragment order ----------------
__global__ __launch_bounds__(256) void k_wpack(const float* __restrict__ w,
                                               unsigned short* __restrict__ wp) {
  const int g = blockIdx.x * 256 + threadIdx.x;
  if (g >= 216 * 64) return;
  const int frag = g >> 6, lane = g & 63;
  const int mb = frag / 24, r = frag % 24, s = r >> 2, i = r & 3;
  const int row = mb * 64 + i * 16 + (lane & 15);
  const int col = s * 32 + (lane >> 4) * 8;
  const float* src = w + (size_t)row * CC + col;
  float4 f0 = *reinterpret_cast<const float4*>(src);
  float4 f1 = *reinterpret_cast<const float4*>(src + 4);
  us4 o0, o1;
  o0[0] = f2bf(f0.x); o0[1] = f2bf(f0.y); o0[2] = f2bf(f0.z); o0[3] = f2bf(f0.w);
  o1[0] = f2bf(f1.x); o1[1] = f2bf(f1.y); o1[2] = f2bf(f1.z); o1[3] = f2bf(f1.w);
  *reinterpret_cast<us4*>(wp + (size_t)g * 8) = o0;
  *reinterpret_cast<us4*>(wp + (size_t)g * 8 + 4) = o1;
}

// ---------------- qkv GEMM: zero-LDS, zero-barrier, FULL-LINE 16B stores ----------------
__global__ __launch_bounds__(512, 4) void k_gemm_qkv(const unsigned short* __restrict__ Wp,
                                                     const unsigned short* __restrict__ XB,
                                                     unsigned short* __restrict__ Y) {
  const int nb = blockIdx.x;  // 64 double-tiles of 256 px
  const int b  = blockIdx.y;
  const int tid = threadIdx.x;
  const int wave = tid >> 6, lane = tid & 63;
  const int lrow = lane & 15;
  const int q8 = (lane >> 4) * 8;
  const int tile = nb * 2 + (wave >> 2), w = wave & 3;

  bfrag bq[2][6];
#pragma unroll
  for (int j = 0; j < 2; ++j)
#pragma unroll
    for (int s = 0; s < 6; ++s)
      bq[j][s] = *reinterpret_cast<const bfrag*>(XB + faddr(b, tile, w, j, s, lane));

  const f32x4 z4 = {0.f, 0.f, 0.f, 0.f};
#pragma unroll 1
  for (int mb = 0; mb < 9; ++mb) {
    const unsigned short* Wb = Wp + (size_t)mb * 24 * 512;
    f32x4 acc[4][2];
#pragma unroll
    for (int i = 0; i < 4; ++i) { acc[i][0] = z4; acc[i][1] = z4; }
#pragma unroll
    for (int s = 0; s < 6; ++s) {
      bfrag af[4];
#pragma unroll
      for (int i = 0; i < 4; ++i)
        af[i] = *reinterpret_cast<const bfrag*>(Wb + ((s * 4 + i) * 64 + lane) * 8);
#pragma unroll
      for (int i = 0; i < 4; ++i) {
        acc[i][0] = MFMA16(bq[0][s], af[i], acc[i][0]);  // D: px permuted, j=low-4px
        acc[i][1] = MFMA16(bq[1][s], af[i], acc[i][1]);  //    j=1 is high-4px of q8 block
      }
    }
    // lane holds 8 CONTIGUOUS px (q8..q8+7) at ch = i*16+lrow: one 16B store per i
    unsigned short* Yb = Y + ((size_t)b * C3 + mb * 64) * HWP + tile * 128 + w * 32 + q8;
#pragma unroll
    for (int i = 0; i < 4; ++i) {
      uint4 pk;
      pk.x = pk2(acc[i][0][0], acc[i][0][1]);
      pk.y = pk2(acc[i][0][2], acc[i][0][3]);
      pk.z = pk2(acc[i][1][0], acc[i][1][1]);
      pk.w = pk2(acc[i][1][2], acc[i][1][3]);
      *reinterpret_cast<uint4*>(Yb + (size_t)(i * 16 + lrow) * HWP) = pk;
    }
  }
}

// ---------------- depthwise 3x3 SAME on q,k channels only (padded strides) ----------------
__global__ __launch_bounds__(256) void k_dwconv(const unsigned short* __restrict__ in,
                                                const float* __restrict__ wd,
                                                unsigned short* __restrict__ outb) {
  const int strip = blockIdx.x;
  const int ch = blockIdx.y;
  const int b = blockIdx.z;
  const int t = threadIdx.x;
  const unsigned short* ip = in + ((size_t)b * C3 + ch) * HWP;
  const float* w = wd + ch * 9;
  const int p = strip * 2048 + t * 8;
  const int y = p >> 7, x0 = p & 127;
  float acc[8] = {0.f, 0.f, 0.f, 0.f, 0.f, 0.f, 0.f, 0.f};
#pragma unroll
  for (int dy = 0; dy < 3; ++dy) {
    int yy = y + dy - 1;
    if (yy < 0 || yy > 127) continue;
    const unsigned short* row = ip + yy * 128;
    bfrag v = *reinterpret_cast<const bfrag*>(row + x0);
    float c[8];
#pragma unroll
    for (int e = 0; e < 8; ++e) c[e] = bf2f_s(v[e]);
    float left  = (x0 > 0)   ? bf2f(row[x0 - 1]) : 0.f;
    float right = (x0 < 120) ? bf2f(row[x0 + 8]) : 0.f;
    float wl = w[dy * 3 + 0], wc = w[dy * 3 + 1], wr = w[dy * 3 + 2];
    acc[0] += wl * left + wc * c[0] + wr * c[1];
#pragma unroll
    for (int e = 1; e < 7; ++e) acc[e] += wl * c[e - 1] + wc * c[e] + wr * c[e + 1];
    acc[7] += wl * c[6] + wc * c[7] + wr * right;
  }
  unsigned short* op = outb + ((size_t)b * 384 + ch) * HWP + p;
  bfrag o;
#pragma unroll
  for (int e = 0; e < 8; ++e) o[e] = (short)f2bf(acc[e]);
  *reinterpret_cast<bfrag*>(op) = o;
}

// ---------------- gram from QKD [b][384][HWP] ----------------
__global__ __launch_bounds__(256) void k_gram(const unsigned short* __restrict__ Qd,
                                              float* __restrict__ S,
                                              float* __restrict__ ssq) {
  const int chunk = blockIdx.x;
  const int h = blockIdx.y, b = blockIdx.z;
  const int tid = threadIdx.x, wave = tid >> 6, lane = tid & 63;
  const int lrow = lane & 15, lk8 = (lane >> 4) * 8;
  const unsigned short* qb = Qd + ((size_t)b * 384 + h * 24) * HWP;
  const unsigned short* kb = qb + (size_t)192 * HWP;
  const int p0 = chunk * 1024 + wave * 256;
  f32x4 acc[2][2];
  const f32x4 z4 = {0.f, 0.f, 0.f, 0.f};
#pragma unroll
  for (int i = 0; i < 2; ++i)
#pragma unroll
    for (int j = 0; j < 2; ++j) acc[i][j] = z4;
  float sq[2] = {0.f, 0.f}, sk[2] = {0.f, 0.f};
  for (int s = 0; s < 8; ++s) {
    const int pp = p0 + s * 32 + lk8;
    bfrag aq[2], bk[2];
#pragma unroll
    for (int i = 0; i < 2; ++i) {
      aq[i] = *reinterpret_cast<const bfrag*>(qb + (size_t)(i * 16 + lrow) * HWP + pp);
      bk[i] = *reinterpret_cast<const bfrag*>(kb + (size_t)(i * 16 + lrow) * HWP + pp);
    }
#pragma unroll
    for (int i = 0; i < 2; ++i) {
#pragma unroll
      for (int e = 0; e < 8; ++e) {
        float qv = bf2f_s(aq[i][e]); sq[i] += qv * qv;
        float kv = bf2f_s(bk[i][e]); sk[i] += kv * kv;
      }
    }
#pragma unroll
    for (int i = 0; i < 2; ++i)
#pragma unroll
      for (int j = 0; j < 2; ++j) acc[i][j] = MFMA16(aq[i], bk[j], acc[i][j]);
  }
  float* Sb = S + (size_t)(b * 8 + h) * 1024;
  const int lr4 = (lane >> 4) * 4;
#pragma unroll
  for (int i = 0; i < 2; ++i)
#pragma unroll
    for (int j = 0; j < 2; ++j)
#pragma unroll
      for (int r = 0; r < 4; ++r)
        atomicAdd(&Sb[(i * 16 + lr4 + r) * 32 + j * 16 + lrow], acc[i][j][r]);
#pragma unroll
  for (int i = 0; i < 2; ++i) {
    float v = sq[i];
    v += __shfl_xor(v, 16); v += __shfl_xor(v, 32);
    float wv = sk[i];
    wv += __shfl_xor(wv, 16); wv += __shfl_xor(wv, 32);
    const int c = i * 16 + lrow;
    if ((lane >> 4) == 0 && c < 24) {
      atomicAdd(&ssq[b * 384 + h * 24 + c], v);
      atomicAdd(&ssq[b * 384 + 192 + h * 24 + c], wv);
    }
  }
}

// ---------------- fused dwconv(v) + transpose -> VT in FRAG order (NATURAL px map) ----
// gemm_out's f32x4 stores are already full-line; VB keeps the original mapping.
__global__ __launch_bounds__(256) void k_dwvt(const unsigned short* __restrict__ QKV,
                                              const float* __restrict__ wd,
                                              unsigned short* __restrict__ VTo) {
  __shared__ unsigned short tile[64 * 72];
  const int pb = blockIdx.x * 64, cb = blockIdx.y * 64, b = blockIdx.z;
  const int t = threadIdx.x;
  const int y = pb >> 7;
  const int xs = pb & 127;
  {
    const int cl = t >> 2, ps = (t & 3) * 16;
    const int gc = 384 + cb + cl;
    const unsigned short* ip = QKV + ((size_t)b * C3 + gc) * HWP;
    const float* w = wd + gc * 9;
    const int x0 = xs + ps;
    float acc[16];
#pragma unroll
    for (int e = 0; e < 16; ++e) acc[e] = 0.f;
#pragma unroll
    for (int dy = 0; dy < 3; ++dy) {
      int yy = y + dy - 1;
      if (yy < 0 || yy > 127) continue;
      const unsigned short* row = ip + yy * 128;
      bfrag v0 = *reinterpret_cast<const bfrag*>(row + x0);
      bfrag v1 = *reinterpret_cast<const bfrag*>(row + x0 + 8);
      float c[16];
#pragma unroll
      for (int e = 0; e < 8; ++e) { c[e] = bf2f_s(v0[e]); c[8 + e] = bf2f_s(v1[e]); }
      float left  = (x0 > 0)   ? bf2f(row[x0 - 1])  : 0.f;
      float right = (x0 < 112) ? bf2f(row[x0 + 16]) : 0.f;
      float wl = w[dy * 3 + 0], wc = w[dy * 3 + 1], wr = w[dy * 3 + 2];
      acc[0] += wl * left + wc * c[0] + wr * c[1];
#pragma unroll
      for (int e = 1; e < 15; ++e) acc[e] += wl * c[e - 1] + wc * c[e] + wr * c[e + 1];
      acc[15] += wl * c[14] + wc * c[15] + wr * right;
    }
    bfrag o0, o1;
#pragma unroll
    for (int e = 0; e < 8; ++e) { o0[e] = (short)f2bf(acc[e]); o1[e] = (short)f2bf(acc[8 + e]); }
    *reinterpret_cast<bfrag*>(&tile[cl * 72 + ps]) = o0;
    *reinterpret_cast<bfrag*>(&tile[cl * 72 + ps + 8]) = o1;
  }
  __syncthreads();
  {
    const int pl = t >> 2, cs = (t & 3) * 16;
    bfrag o0, o1;
#pragma unroll
    for (int e = 0; e < 8; ++e) o0[e] = (short)tile[(cs + e) * 72 + pl];
#pragma unroll
    for (int e = 0; e < 8; ++e) o1[e] = (short)tile[(cs + 8 + e) * 72 + pl];
    const int P = pb + pl, ch0 = cb + cs;
    const int ti = P >> 7, pit = P & 127;
    const int w = pit >> 5, j = (pit >> 4) & 1, pxl = pit & 15;
    const int s0 = ch0 >> 5, kh0 = (ch0 >> 3) & 3;
    const int ch1 = ch0 + 8, s1 = ch1 >> 5, kh1 = (ch1 >> 3) & 3;
    *reinterpret_cast<bfrag*>(VTo + faddr(b, ti, w, j, s0, pxl + 16 * kh0)) = o0;
    *reinterpret_cast<bfrag*>(VTo + faddr(b, ti, w, j, s1, pxl + 16 * kh1)) = o1;
  }
}

// ---------------- softmax + M = wproj @ blockdiag(attn), written PACKED ----------------
__global__ __launch_bounds__(64) void k_attn(const float* __restrict__ S,
                                             const float* __restrict__ ssq,
                                             const float* __restrict__ wproj,
                                             const float* __restrict__ temp,
                                             unsigned short* __restrict__ Mp) {
  const int h = blockIdx.x, b = blockIdx.y;
  __shared__ float A[24][25];
  __shared__ float nq[24], nk[24];
  const float* Sb = S + (size_t)(b * 8 + h) * 1024;
  const float* sq = ssq + b * 384 + h * 24;
  const float* sk = ssq + b * 384 + 192 + h * 24;
  const int t = threadIdx.x;
  if (t < 24) {
    nq[t] = fmaxf(sqrtf(sq[t]), 1e-12f);
    nk[t] = fmaxf(sqrtf(sk[t]), 1e-12f);
  }
  __syncthreads();
  if (t < 24) {
    const float tp = temp[h];
    float row[24];
    float mx = -1e30f;
#pragma unroll
    for (int d = 0; d < 24; ++d) {
      row[d] = Sb[t * 32 + d] / (nq[t] * nk[d]) * tp;
      mx = fmaxf(mx, row[d]);
    }
    float s = 0.f;
#pragma unroll
    for (int d = 0; d < 24; ++d) { row[d] = __expf(row[d] - mx); s += row[d]; }
    const float inv = 1.f / s;
#pragma unroll
    for (int d = 0; d < 24; ++d) A[t][d] = row[d] * inv;
  }
  __syncthreads();
  for (int idx = t; idx < 192 * 24; idx += 64) {
    const int o = idx / 24, dd = idx % 24;
    const float* wrow = wproj + o * 192 + h * 24;
    float a = 0.f;
#pragma unroll
    for (int cc = 0; cc < 24; ++cc) a += wrow[cc] * A[cc][dd];
    const int c = h * 24 + dd;
    const int mb = o >> 6, i = (o >> 4) & 3, lr = o & 15;
    const int s = c >> 5, hi = (c >> 3) & 3, e = c & 7;
    const int off = ((mb * 24 + s * 4 + i) * 64 + hi * 16 + lr) * 8 + e;
    Mp[(size_t)b * CC * CC + off] = f2bf(a);
  }
}

// ---------------- out GEMM: zero-LDS, zero-barrier (frag-order VT, natural px) ----------
__global__ __launch_bounds__(512, 4) void k_gemm_out(const unsigned short* __restrict__ Mp,
                                                     const unsigned short* __restrict__ VB,
                                                     float* __restrict__ out) {
  const int nb = blockIdx.x;  // 64 double-tiles of 256 px
  const int b  = blockIdx.y;
  const int tid = threadIdx.x;
  const int wave = tid >> 6, lane = tid & 63;
  const int lrow = lane & 15, lr4 = (lane >> 4) * 4;
  const int tile = nb * 2 + (wave >> 2), w = wave & 3;

  bfrag bq[2][6];
#pragma unroll
  for (int j = 0; j < 2; ++j)
#pragma unroll
    for (int s = 0; s < 6; ++s)
      bq[j][s] = *reinterpret_cast<const bfrag*>(VB + faddr(b, tile, w, j, s, lane));

  const f32x4 z4 = {0.f, 0.f, 0.f, 0.f};
#pragma unroll 1
  for (int mb = 0; mb < 3; ++mb) {
    const unsigned short* Mb = Mp + (size_t)b * CC * CC + (size_t)mb * 24 * 512;
    f32x4 acc[4][2];
#pragma unroll
    for (int i = 0; i < 4; ++i) { acc[i][0] = z4; acc[i][1] = z4; }
#pragma unroll
    for (int s = 0; s < 6; ++s) {
      bfrag af[4];
#pragma unroll
      for (int i = 0; i < 4; ++i)
        af[i] = *reinterpret_cast<const bfrag*>(Mb + ((s * 4 + i) * 64 + lane) * 8);
#pragma unroll
      for (int i = 0; i < 4; ++i) {
        acc[i][0] = MFMA16(bq[0][s], af[i], acc[i][0]);  // D[px][ch]
        acc[i][1] = MFMA16(bq[1][s], af[i], acc[i][1]);
      }
    }
    float* Ob = out + ((size_t)b * CC + mb * 64) * HW + tile * 128 + w * 32;
#pragma unroll
    for (int i = 0; i < 4; ++i) {
      float* rp = Ob + (size_t)(i * 16 + lrow) * HW;
#pragma unroll
      for (int j = 0; j < 2; ++j)
        *reinterpret_cast<f32x4*>(rp + j * 16 + lr4) = acc[i][j];
    }
  }
}

extern "C" void kernel_launch(void* const* d_in, const int* in_sizes, int n_in,
                              void* d_out, int out_size, void* d_ws, size_t ws_size,
                              hipStream_t stream) {
  const float* x      = (const float*)d_in[0];
  const float* w_qkv  = (const float*)d_in[1];
  const float* w_dw   = (const float*)d_in[2];
  const float* w_proj = (const float*)d_in[3];
  const float* temp   = (const float*)d_in[4];
  float* out = (float*)d_out;
  char* ws = (char*)d_ws;

  unsigned short* XB   = (unsigned short*)(ws + OFF_XT);
  unsigned short* VB   = (unsigned short*)(ws + OFF_XT);  // reuse: XB dead after qkv GEMM
  unsigned short* WP   = (unsigned short*)(ws + OFF_WQ);
  unsigned short* QKV  = (unsigned short*)(ws + OFF_QKV);
  unsigned short* QKD  = (unsigned short*)(ws + OFF_QKD);
  float* S   = (float*)(ws + OFF_S);
  float* SSQ = (float*)(ws + OFF_SSQ);
  unsigned short* MP  = (unsigned short*)(ws + OFF_M);

  hipMemsetAsync(ws + OFF_S, 0, SZ_S + SZ_SSQ, stream);
  k_wpack<<<54, 256, 0, stream>>>(w_qkv, WP);
  k_xt<<<dim3(HW / 64, CC / 64, NB), 256, 0, stream>>>(x, XB);
  k_gemm_qkv<<<dim3(64, NB), 512, 0, stream>>>(WP, XB, QKV);
  k_dwconv<<<dim3(8, 384, NB), 256, 0, stream>>>(QKV, w_dw, QKD);
  k_dwvt<<<dim3(HW / 64, 3, NB), 256, 0, stream>>>(QKV, w_dw, VB);
  k_gram<<<dim3(16, NH, NB), 256, 0, stream>>>(QKD, S, SSQ);
  k_attn<<<dim3(NH, NB), 64, 0, stream>>>(S, SSQ, w_proj, temp, MP);
  k_gemm_out<<<dim3(64, NB), 512, 0, stream>>>(MP, VB, out);
}

// Round 16
// 294.556 us; speedup vs baseline: 1.2000x; 1.0249x over previous
//
#include <hip/hip_runtime.h>

#define HW 16384
#define HWP 16416   // padded channel stride (+32 px = +64B): breaks 32KB power-of-2 L2-channel camping
#define CC 192
#define C3 576
#define NB 8
#define NH 8

typedef __attribute__((ext_vector_type(8))) short bfrag;
typedef __attribute__((ext_vector_type(4))) float f32x4;
typedef __attribute__((ext_vector_type(4))) unsigned short us4;

#define MFMA16(a, b, c) __builtin_amdgcn_mfma_f32_16x16x32_bf16(a, b, c, 0, 0, 0)

__device__ __forceinline__ unsigned short f2bf(float f) {
  unsigned int u = __float_as_uint(f);
  u += 0x7fffu + ((u >> 16) & 1u);
  return (unsigned short)(u >> 16);
}
__device__ __forceinline__ float bf2f(unsigned short s) {
  return __uint_as_float(((unsigned int)s) << 16);
}
__device__ __forceinline__ float bf2f_s(short s) {
  return __uint_as_float(((unsigned int)(unsigned short)s) << 16);
}
__device__ __forceinline__ unsigned int pk2(float lo, float hi) {
  return (unsigned int)f2bf(lo) | ((unsigned int)f2bf(hi) << 16);
}

// fragment-order address (elements) for B operands:
// frag (tile,w,j,s), lane = row + 16*khalf, 8 contiguous ch elements per lane
__device__ __forceinline__ size_t faddr(int b, int tile, int w, int j, int s, int lane) {
  return ((((((size_t)b * 128 + tile) * 4 + w) * 2 + j) * 6 + s) * 512 + (size_t)lane * 8);
}

// ---------------- workspace layout (bytes) ----------------
#define OFF_XT   0ull
#define SZ_XT    ((size_t)NB * HW * CC * 2)      // x bf16 in FRAG order; later reused as VT (frag order)
#define OFF_WQ   (OFF_XT + SZ_XT)
#define SZ_WQ    ((size_t)C3 * CC * 2)           // W packed into MFMA frag order
#define OFF_QKV  (OFF_WQ + SZ_WQ)
#define SZ_QKV   ((size_t)NB * C3 * HWP * 2)     // qkv (pre-dw) bf16 [b][576][HWP]
#define OFF_QKD  (OFF_QKV + SZ_QKV)
#define SZ_QKD   ((size_t)NB * 384 * HWP * 2)    // post-dw q,k only [b][384][HWP]
#define OFF_S    (OFF_QKD + SZ_QKD)
#define SZ_S     ((size_t)NB * NH * 32 * 32 * 4) // gram fp32 [b][h][32][32]
#define OFF_SSQ  (OFF_S + SZ_S)
#define SZ_SSQ   ((size_t)NB * 384 * 4)          // sumsq fp32 [b][q:192 | k:192]
#define OFF_M    (OFF_SSQ + SZ_SSQ)
#define SZ_M     ((size_t)NB * CC * CC * 2)      // fused proj*attn, packed frag order

// ---------------- prep: x -> bf16 FRAG-ORDER, px PERMUTED for full-line GEMM stores ----
__global__ __launch_bounds__(256) void k_xt(const float* __restrict__ x,
                                            unsigned short* __restrict__ xb) {
  __shared__ unsigned short tile[64 * 72];
  const int pb = blockIdx.x * 64;
  const int cb = blockIdx.y * 64;
  const int b  = blockIdx.z;
  const int t  = threadIdx.x;
  {
    const int cl = t >> 2, pl = (t & 3) * 16;
    const float* src = x + ((size_t)b * CC + cb + cl) * HW + pb + pl;
    bfrag v0, v1;
#pragma unroll
    for (int q4 = 0; q4 < 2; ++q4) {
      float4 f = *reinterpret_cast<const float4*>(src + q4 * 4);
      v0[q4 * 4 + 0] = (short)f2bf(f.x); v0[q4 * 4 + 1] = (short)f2bf(f.y);
      v0[q4 * 4 + 2] = (short)f2bf(f.z); v0[q4 * 4 + 3] = (short)f2bf(f.w);
    }
#pragma unroll
    for (int q4 = 0; q4 < 2; ++q4) {
      float4 f = *reinterpret_cast<const float4*>(src + 8 + q4 * 4);
      v1[q4 * 4 + 0] = (short)f2bf(f.x); v1[q4 * 4 + 1] = (short)f2bf(f.y);
      v1[q4 * 4 + 2] = (short)f2bf(f.z); v1[q4 * 4 + 3] = (short)f2bf(f.w);
    }
    *reinterpret_cast<bfrag*>(&tile[cl * 72 + pl]) = v0;
    *reinterpret_cast<bfrag*>(&tile[cl * 72 + pl + 8]) = v1;
  }
  __syncthreads();
  {
    const int pl = t >> 2, cl = (t & 3) * 16;
    bfrag o0, o1;
#pragma unroll
    for (int e = 0; e < 8; ++e) o0[e] = (short)tile[(cl + e) * 72 + pl];
#pragma unroll
    for (int e = 0; e < 8; ++e) o1[e] = (short)tile[(cl + 8 + e) * 72 + pl];
    const int P = pb + pl, ch0 = cb + cl;
    const int ti = P >> 7, pit = P & 127;
    const int w = pit >> 5, p32 = pit & 31;
    const int j = (p32 >> 2) & 1;
    const int r = ((p32 >> 3) << 2) | (p32 & 3);
    const int s0 = ch0 >> 5, kh0 = (ch0 >> 3) & 3;
    const int ch1 = ch0 + 8, s1 = ch1 >> 5, kh1 = (ch1 >> 3) & 3;
    *reinterpret_cast<bfrag*>(xb + faddr(b, ti, w, j, s0, r + 16 * kh0)) = o0;
    *reinterpret_cast<bfrag*>(xb + faddr(b, ti, w, j, s1, r + 16 * kh1)) = o1;
  }
}

// ---------------- prep: pack W into MFMA fragment order ----------------
__global__ __launch_bounds__(256) void k_wpack(const float* __restrict__ w,
                                               unsigned short* __restrict__ wp) {
  const int g = blockIdx.x * 256 + threadIdx.x;
  if (g >= 216 * 64) return;
  const int frag = g >> 6, lane = g & 63;
  const int mb = frag / 24, r = frag % 24, s = r >> 2, i = r & 3;
  const int row = mb * 64 + i * 16 + (lane & 15);
  const int col = s * 32 + (lane >> 4) * 8;
  const float* src = w + (size_t)row * CC + col;
  float4 f0 = *reinterpret_cast<const float4*>(src);
  float4 f1 = *reinterpret_cast<const float4*>(src + 4);
  us4 o0, o1;
  o0[0] = f2bf(f0.x); o0[1] = f2bf(f0.y); o0[2] = f2bf(f0.z); o0[3] = f2bf(f0.w);
  o1[0] = f2bf(f1.x); o1[1] = f2bf(f1.y); o1[2] = f2bf(f1.z); o1[3] = f2bf(f1.w);
  *reinterpret_cast<us4*>(wp + (size_t)g * 8) = o0;
  *reinterpret_cast<us4*>(wp + (size_t)g * 8 + 4) = o1;
}

// ---------------- qkv GEMM: zero-LDS, zero-barrier, FULL-LINE 16B stores ----------------
__global__ __launch_bounds__(512, 4) void k_gemm_qkv(const unsigned short* __restrict__ Wp,
                                                     const unsigned short* __restrict__ XB,
                                                     unsigned short* __restrict__ Y) {
  const int nb = blockIdx.x;  // 64 double-tiles of 256 px
  const int b  = blockIdx.y;
  const int tid = threadIdx.x;
  const int wave = tid >> 6, lane = tid & 63;
  const int lrow = lane & 15;
  const int q8 = (lane >> 4) * 8;
  const int tile = nb * 2 + (wave >> 2), w = wave & 3;

  bfrag bq[2][6];
#pragma unroll
  for (int j = 0; j < 2; ++j)
#pragma unroll
    for (int s = 0; s < 6; ++s)
      bq[j][s] = *reinterpret_cast<const bfrag*>(XB + faddr(b, tile, w, j, s, lane));

  const f32x4 z4 = {0.f, 0.f, 0.f, 0.f};
#pragma unroll 1
  for (int mb = 0; mb < 9; ++mb) {
    const unsigned short* Wb = Wp + (size_t)mb * 24 * 512;
    f32x4 acc[4][2];
#pragma unroll
    for (int i = 0; i < 4; ++i) { acc[i][0] = z4; acc[i][1] = z4; }
#pragma unroll
    for (int s = 0; s < 6; ++s) {
      bfrag af[4];
#pragma unroll
      for (int i = 0; i < 4; ++i)
        af[i] = *reinterpret_cast<const bfrag*>(Wb + ((s * 4 + i) * 64 + lane) * 8);
#pragma unroll
      for (int i = 0; i < 4; ++i) {
        acc[i][0] = MFMA16(bq[0][s], af[i], acc[i][0]);
        acc[i][1] = MFMA16(bq[1][s], af[i], acc[i][1]);
      }
    }
    unsigned short* Yb = Y + ((size_t)b * C3 + mb * 64) * HWP + tile * 128 + w * 32 + q8;
#pragma unroll
    for (int i = 0; i < 4; ++i) {
      uint4 pk;
      pk.x = pk2(acc[i][0][0], acc[i][0][1]);
      pk.y = pk2(acc[i][0][2], acc[i][0][3]);
      pk.z = pk2(acc[i][1][0], acc[i][1][1]);
      pk.w = pk2(acc[i][1][2], acc[i][1][3]);
      *reinterpret_cast<uint4*>(Yb + (size_t)(i * 16 + lrow) * HWP) = pk;
    }
  }
}

// ---------------- depthwise 3x3 SAME on q,k: stencil reuse + shfl halos ----------------
// Thread = 8-px column x 2 output rows. 4 input rows loaded ONCE to registers
// (amplification 3.0 -> 2.0); L/R halos via __shfl of neighbor lanes (proven in R11's
// dwconv4) -> zero halo loads. VMEM/thread: 4 loads + 2 stores (was 9+1 per row).
__global__ __launch_bounds__(256) void k_dwconv(const unsigned short* __restrict__ in,
                                                const float* __restrict__ wd,
                                                unsigned short* __restrict__ outb) {
  const int band = blockIdx.x;   // 4 bands of 32 output rows
  const int ch = blockIdx.y;     // 384 (q,k channels)
  const int b = blockIdx.z;
  const int t = threadIdx.x;
  const unsigned short* ip = in + ((size_t)b * C3 + ch) * HWP;
  const float* w = wd + ch * 9;
  const int xg = t & 15, x0 = xg * 8;
  const int y0 = band * 32 + (t >> 4) * 2;

  float c[4][8];
#pragma unroll
  for (int r = 0; r < 4; ++r) {
    const int yy = y0 - 1 + r;
    if (yy < 0 || yy > 127) {
#pragma unroll
      for (int e = 0; e < 8; ++e) c[r][e] = 0.f;
    } else {
      bfrag v = *reinterpret_cast<const bfrag*>(ip + yy * 128 + x0);
#pragma unroll
      for (int e = 0; e < 8; ++e) c[r][e] = bf2f_s(v[e]);
    }
  }
  float L[4], R[4];
#pragma unroll
  for (int r = 0; r < 4; ++r) {
    const float l = __shfl_up(c[r][7], 1);
    L[r] = (xg == 0) ? 0.f : l;       // row start: SAME padding -> 0
    const float rr = __shfl_down(c[r][0], 1);
    R[r] = (xg == 15) ? 0.f : rr;     // row end
  }
  unsigned short* op = outb + ((size_t)b * 384 + ch) * HWP;
#pragma unroll
  for (int i = 0; i < 2; ++i) {
    float acc[8];
#pragma unroll
    for (int e = 0; e < 8; ++e) acc[e] = 0.f;
#pragma unroll
    for (int dy = 0; dy < 3; ++dy) {
      const int r = i + dy;
      const float wl = w[dy * 3 + 0], wc = w[dy * 3 + 1], wr = w[dy * 3 + 2];
      acc[0] += wl * L[r] + wc * c[r][0] + wr * c[r][1];
#pragma unroll
      for (int e = 1; e < 7; ++e) acc[e] += wl * c[r][e - 1] + wc * c[r][e] + wr * c[r][e + 1];
      acc[7] += wl * c[r][6] + wc * c[r][7] + wr * R[r];
    }
    bfrag o;
#pragma unroll
    for (int e = 0; e < 8; ++e) o[e] = (short)f2bf(acc[e]);
    *reinterpret_cast<bfrag*>(op + (size_t)(y0 + i) * 128 + x0) = o;
  }
}

// ---------------- gram from QKD [b][384][HWP] ----------------
__global__ __launch_bounds__(256) void k_gram(const unsigned short* __restrict__ Qd,
                                              float* __restrict__ S,
                                              float* __restrict__ ssq) {
  const int chunk = blockIdx.x;
  const int h = blockIdx.y, b = blockIdx.z;
  const int tid = threadIdx.x, wave = tid >> 6, lane = tid & 63;
  const int lrow = lane & 15, lk8 = (lane >> 4) * 8;
  const unsigned short* qb = Qd + ((size_t)b * 384 + h * 24) * HWP;
  const unsigned short* kb = qb + (size_t)192 * HWP;
  const int p0 = chunk * 1024 + wave * 256;
  f32x4 acc[2][2];
  const f32x4 z4 = {0.f, 0.f, 0.f, 0.f};
#pragma unroll
  for (int i = 0; i < 2; ++i)
#pragma unroll
    for (int j = 0; j < 2; ++j) acc[i][j] = z4;
  float sq[2] = {0.f, 0.f}, sk[2] = {0.f, 0.f};
  for (int s = 0; s < 8; ++s) {
    const int pp = p0 + s * 32 + lk8;
    bfrag aq[2], bk[2];
#pragma unroll
    for (int i = 0; i < 2; ++i) {
      aq[i] = *reinterpret_cast<const bfrag*>(qb + (size_t)(i * 16 + lrow) * HWP + pp);
      bk[i] = *reinterpret_cast<const bfrag*>(kb + (size_t)(i * 16 + lrow) * HWP + pp);
    }
#pragma unroll
    for (int i = 0; i < 2; ++i) {
#pragma unroll
      for (int e = 0; e < 8; ++e) {
        float qv = bf2f_s(aq[i][e]); sq[i] += qv * qv;
        float kv = bf2f_s(bk[i][e]); sk[i] += kv * kv;
      }
    }
#pragma unroll
    for (int i = 0; i < 2; ++i)
#pragma unroll
      for (int j = 0; j < 2; ++j) acc[i][j] = MFMA16(aq[i], bk[j], acc[i][j]);
  }
  float* Sb = S + (size_t)(b * 8 + h) * 1024;
  const int lr4 = (lane >> 4) * 4;
#pragma unroll
  for (int i = 0; i < 2; ++i)
#pragma unroll
    for (int j = 0; j < 2; ++j)
#pragma unroll
      for (int r = 0; r < 4; ++r)
        atomicAdd(&Sb[(i * 16 + lr4 + r) * 32 + j * 16 + lrow], acc[i][j][r]);
#pragma unroll
  for (int i = 0; i < 2; ++i) {
    float v = sq[i];
    v += __shfl_xor(v, 16); v += __shfl_xor(v, 32);
    float wv = sk[i];
    wv += __shfl_xor(wv, 16); wv += __shfl_xor(wv, 32);
    const int c = i * 16 + lrow;
    if ((lane >> 4) == 0 && c < 24) {
      atomicAdd(&ssq[b * 384 + h * 24 + c], v);
      atomicAdd(&ssq[b * 384 + 192 + h * 24 + c], wv);
    }
  }
}

// ---------------- fused dwconv(v) + transpose -> VT in FRAG order (NATURAL px map) ----
__global__ __launch_bounds__(256) void k_dwvt(const unsigned short* __restrict__ QKV,
                                              const float* __restrict__ wd,
                                              unsigned short* __restrict__ VTo) {
  __shared__ unsigned short tile[64 * 72];
  const int pb = blockIdx.x * 64, cb = blockIdx.y * 64, b = blockIdx.z;
  const int t = threadIdx.x;
  const int y = pb >> 7;
  const int xs = pb & 127;
  {
    const int cl = t >> 2, ps = (t & 3) * 16;
    const int gc = 384 + cb + cl;
    const unsigned short* ip = QKV + ((size_t)b * C3 + gc) * HWP;
    const float* w = wd + gc * 9;
    const int x0 = xs + ps;
    float acc[16];
#pragma unroll
    for (int e = 0; e < 16; ++e) acc[e] = 0.f;
#pragma unroll
    for (int dy = 0; dy < 3; ++dy) {
      int yy = y + dy - 1;
      if (yy < 0 || yy > 127) continue;
      const unsigned short* row = ip + yy * 128;
      bfrag v0 = *reinterpret_cast<const bfrag*>(row + x0);
      bfrag v1 = *reinterpret_cast<const bfrag*>(row + x0 + 8);
      float c[16];
#pragma unroll
      for (int e = 0; e < 8; ++e) { c[e] = bf2f_s(v0[e]); c[8 + e] = bf2f_s(v1[e]); }
      float left  = (x0 > 0)   ? bf2f(row[x0 - 1])  : 0.f;
      float right = (x0 < 112) ? bf2f(row[x0 + 16]) : 0.f;
      float wl = w[dy * 3 + 0], wc = w[dy * 3 + 1], wr = w[dy * 3 + 2];
      acc[0] += wl * left + wc * c[0] + wr * c[1];
#pragma unroll
      for (int e = 1; e < 15; ++e) acc[e] += wl * c[e - 1] + wc * c[e] + wr * c[e + 1];
      acc[15] += wl * c[14] + wc * c[15] + wr * right;
    }
    bfrag o0, o1;
#pragma unroll
    for (int e = 0; e < 8; ++e) { o0[e] = (short)f2bf(acc[e]); o1[e] = (short)f2bf(acc[8 + e]); }
    *reinterpret_cast<bfrag*>(&tile[cl * 72 + ps]) = o0;
    *reinterpret_cast<bfrag*>(&tile[cl * 72 + ps + 8]) = o1;
  }
  __syncthreads();
  {
    const int pl = t >> 2, cs = (t & 3) * 16;
    bfrag o0, o1;
#pragma unroll
    for (int e = 0; e < 8; ++e) o0[e] = (short)tile[(cs + e) * 72 + pl];
#pragma unroll
    for (int e = 0; e < 8; ++e) o1[e] = (short)tile[(cs + 8 + e) * 72 + pl];
    const int P = pb + pl, ch0 = cb + cs;
    const int ti = P >> 7, pit = P & 127;
    const int w = pit >> 5, j = (pit >> 4) & 1, pxl = pit & 15;
    const int s0 = ch0 >> 5, kh0 = (ch0 >> 3) & 3;
    const int ch1 = ch0 + 8, s1 = ch1 >> 5, kh1 = (ch1 >> 3) & 3;
    *reinterpret_cast<bfrag*>(VTo + faddr(b, ti, w, j, s0, pxl + 16 * kh0)) = o0;
    *reinterpret_cast<bfrag*>(VTo + faddr(b, ti, w, j, s1, pxl + 16 * kh1)) = o1;
  }
}

// ---------------- softmax + M = wproj @ blockdiag(attn), written PACKED ----------------
__global__ __launch_bounds__(64) void k_attn(const float* __restrict__ S,
                                             const float* __restrict__ ssq,
                                             const float* __restrict__ wproj,
                                             const float* __restrict__ temp,
                                             unsigned short* __restrict__ Mp) {
  const int h = blockIdx.x, b = blockIdx.y;
  __shared__ float A[24][25];
  __shared__ float nq[24], nk[24];
  const float* Sb = S + (size_t)(b * 8 + h) * 1024;
  const float* sq = ssq + b * 384 + h * 24;
  const float* sk = ssq + b * 384 + 192 + h * 24;
  const int t = threadIdx.x;
  if (t < 24) {
    nq[t] = fmaxf(sqrtf(sq[t]), 1e-12f);
    nk[t] = fmaxf(sqrtf(sk[t]), 1e-12f);
  }
  __syncthreads();
  if (t < 24) {
    const float tp = temp[h];
    float row[24];
    float mx = -1e30f;
#pragma unroll
    for (int d = 0; d < 24; ++d) {
      row[d] = Sb[t * 32 + d] / (nq[t] * nk[d]) * tp;
      mx = fmaxf(mx, row[d]);
    }
    float s = 0.f;
#pragma unroll
    for (int d = 0; d < 24; ++d) { row[d] = __expf(row[d] - mx); s += row[d]; }
    const float inv = 1.f / s;
#pragma unroll
    for (int d = 0; d < 24; ++d) A[t][d] = row[d] * inv;
  }
  __syncthreads();
  for (int idx = t; idx < 192 * 24; idx += 64) {
    const int o = idx / 24, dd = idx % 24;
    const float* wrow = wproj + o * 192 + h * 24;
    float a = 0.f;
#pragma unroll
    for (int cc = 0; cc < 24; ++cc) a += wrow[cc] * A[cc][dd];
    const int c = h * 24 + dd;
    const int mb = o >> 6, i = (o >> 4) & 3, lr = o & 15;
    const int s = c >> 5, hi = (c >> 3) & 3, e = c & 7;
    const int off = ((mb * 24 + s * 4 + i) * 64 + hi * 16 + lr) * 8 + e;
    Mp[(size_t)b * CC * CC + off] = f2bf(a);
  }
}

// ---------------- out GEMM: zero-LDS, zero-barrier (frag-order VT, natural px) ----------
__global__ __launch_bounds__(512, 4) void k_gemm_out(const unsigned short* __restrict__ Mp,
                                                     const unsigned short* __restrict__ VB,
                                                     float* __restrict__ out) {
  const int nb = blockIdx.x;  // 64 double-tiles of 256 px
  const int b  = blockIdx.y;
  const int tid = threadIdx.x;
  const int wave = tid >> 6, lane = tid & 63;
  const int lrow = lane & 15, lr4 = (lane >> 4) * 4;
  const int tile = nb * 2 + (wave >> 2), w = wave & 3;

  bfrag bq[2][6];
#pragma unroll
  for (int j = 0; j < 2; ++j)
#pragma unroll
    for (int s = 0; s < 6; ++s)
      bq[j][s] = *reinterpret_cast<const bfrag*>(VB + faddr(b, tile, w, j, s, lane));

  const f32x4 z4 = {0.f, 0.f, 0.f, 0.f};
#pragma unroll 1
  for (int mb = 0; mb < 3; ++mb) {
    const unsigned short* Mb = Mp + (size_t)b * CC * CC + (size_t)mb * 24 * 512;
    f32x4 acc[4][2];
#pragma unroll
    for (int i = 0; i < 4; ++i) { acc[i][0] = z4; acc[i][1] = z4; }
#pragma unroll
    for (int s = 0; s < 6; ++s) {
      bfrag af[4];
#pragma unroll
      for (int i = 0; i < 4; ++i)
        af[i] = *reinterpret_cast<const bfrag*>(Mb + ((s * 4 + i) * 64 + lane) * 8);
#pragma unroll
      for (int i = 0; i < 4; ++i) {
        acc[i][0] = MFMA16(bq[0][s], af[i], acc[i][0]);  // D[px][ch]
        acc[i][1] = MFMA16(bq[1][s], af[i], acc[i][1]);
      }
    }
    float* Ob = out + ((size_t)b * CC + mb * 64) * HW + tile * 128 + w * 32;
#pragma unroll
    for (int i = 0; i < 4; ++i) {
      float* rp = Ob + (size_t)(i * 16 + lrow) * HW;
#pragma unroll
      for (int j = 0; j < 2; ++j)
        *reinterpret_cast<f32x4*>(rp + j * 16 + lr4) = acc[i][j];
    }
  }
}

extern "C" void kernel_launch(void* const* d_in, const int* in_sizes, int n_in,
                              void* d_out, int out_size, void* d_ws, size_t ws_size,
                              hipStream_t stream) {
  const float* x      = (const float*)d_in[0];
  const float* w_qkv  = (const float*)d_in[1];
  const float* w_dw   = (const float*)d_in[2];
  const float* w_proj = (const float*)d_in[3];
  const float* temp   = (const float*)d_in[4];
  float* out = (float*)d_out;
  char* ws = (char*)d_ws;

  unsigned short* XB   = (unsigned short*)(ws + OFF_XT);
  unsigned short* VB   = (unsigned short*)(ws + OFF_XT);  // reuse: XB dead after qkv GEMM
  unsigned short* WP   = (unsigned short*)(ws + OFF_WQ);
  unsigned short* QKV  = (unsigned short*)(ws + OFF_QKV);
  unsigned short* QKD  = (unsigned short*)(ws + OFF_QKD);
  float* S   = (float*)(ws + OFF_S);
  float* SSQ = (float*)(ws + OFF_SSQ);
  unsigned short* MP  = (unsigned short*)(ws + OFF_M);

  hipMemsetAsync(ws + OFF_S, 0, SZ_S + SZ_SSQ, stream);
  k_wpack<<<54, 256, 0, stream>>>(w_qkv, WP);
  k_xt<<<dim3(HW / 64, CC / 64, NB), 256, 0, stream>>>(x, XB);
  k_gemm_qkv<<<dim3(64, NB), 512, 0, stream>>>(WP, XB, QKV);
  k_dwconv<<<dim3(4, 384, NB), 256, 0, stream>>>(QKV, w_dw, QKD);
  k_dwvt<<<dim3(HW / 64, 3, NB), 256, 0, stream>>>(QKV, w_dw, VB);
  k_gram<<<dim3(16, NH, NB), 256, 0, stream>>>(QKD, S, SSQ);
  k_attn<<<dim3(NH, NB), 64, 0, stream>>>(S, SSQ, w_proj, temp, MP);
  k_gemm_out<<<dim3(64, NB), 512, 0, stream>>>(MP, VB, out);
}

// Round 17
// 288.458 us; speedup vs baseline: 1.2254x; 1.0211x over previous
//
#include <hip/hip_runtime.h>

#define HW 16384
#define HWP 16416   // padded channel stride (+32 px = +64B): breaks 32KB power-of-2 L2-channel camping
#define CC 192
#define C3 576
#define NB 8
#define NH 8

typedef __attribute__((ext_vector_type(8))) short bfrag;
typedef __attribute__((ext_vector_type(4))) float f32x4;
typedef __attribute__((ext_vector_type(4))) unsigned short us4;

#define MFMA16(a, b, c) __builtin_amdgcn_mfma_f32_16x16x32_bf16(a, b, c, 0, 0, 0)

__device__ __forceinline__ unsigned short f2bf(float f) {
  unsigned int u = __float_as_uint(f);
  u += 0x7fffu + ((u >> 16) & 1u);
  return (unsigned short)(u >> 16);
}
__device__ __forceinline__ float bf2f(unsigned short s) {
  return __uint_as_float(((unsigned int)s) << 16);
}
__device__ __forceinline__ float bf2f_s(short s) {
  return __uint_as_float(((unsigned int)(unsigned short)s) << 16);
}
__device__ __forceinline__ unsigned int pk2(float lo, float hi) {
  return (unsigned int)f2bf(lo) | ((unsigned int)f2bf(hi) << 16);
}

// fragment-order address (elements) for B operands:
// frag (tile,w,j,s), lane = row + 16*khalf, 8 contiguous ch elements per lane
__device__ __forceinline__ size_t faddr(int b, int tile, int w, int j, int s, int lane) {
  return ((((((size_t)b * 128 + tile) * 4 + w) * 2 + j) * 6 + s) * 512 + (size_t)lane * 8);
}

// ---------------- workspace layout (bytes) ----------------
#define OFF_XT   0ull
#define SZ_XT    ((size_t)NB * HW * CC * 2)      // x bf16 in FRAG order; later reused as VT (frag order)
#define OFF_WQ   (OFF_XT + SZ_XT)
#define SZ_WQ    ((size_t)C3 * CC * 2)           // W packed into MFMA frag order
#define OFF_QKV  (OFF_WQ + SZ_WQ)
#define SZ_QKV   ((size_t)NB * C3 * HWP * 2)     // qkv (pre-dw) bf16 [b][576][HWP]
#define OFF_QKD  (OFF_QKV + SZ_QKV)
#define SZ_QKD   ((size_t)NB * 384 * HWP * 2)    // post-dw q,k only [b][384][HWP]
#define OFF_S    (OFF_QKD + SZ_QKD)
#define SZ_S     ((size_t)NB * NH * 32 * 32 * 4) // gram fp32 [b][h][32][32]
#define OFF_SSQ  (OFF_S + SZ_S)
#define SZ_SSQ   ((size_t)NB * 384 * 4)          // sumsq fp32 [b][q:192 | k:192]
#define OFF_M    (OFF_SSQ + SZ_SSQ)
#define SZ_M     ((size_t)NB * CC * CC * 2)      // fused proj*attn, packed frag order

// ---------------- prep: x -> bf16 FRAG-ORDER, px PERMUTED for full-line GEMM stores ----
__global__ __launch_bounds__(256) void k_xt(const float* __restrict__ x,
                                            unsigned short* __restrict__ xb) {
  __shared__ unsigned short tile[64 * 72];
  const int pb = blockIdx.x * 64;
  const int cb = blockIdx.y * 64;
  const int b  = blockIdx.z;
  const int t  = threadIdx.x;
  {
    const int cl = t >> 2, pl = (t & 3) * 16;
    const float* src = x + ((size_t)b * CC + cb + cl) * HW + pb + pl;
    bfrag v0, v1;
#pragma unroll
    for (int q4 = 0; q4 < 2; ++q4) {
      float4 f = *reinterpret_cast<const float4*>(src + q4 * 4);
      v0[q4 * 4 + 0] = (short)f2bf(f.x); v0[q4 * 4 + 1] = (short)f2bf(f.y);
      v0[q4 * 4 + 2] = (short)f2bf(f.z); v0[q4 * 4 + 3] = (short)f2bf(f.w);
    }
#pragma unroll
    for (int q4 = 0; q4 < 2; ++q4) {
      float4 f = *reinterpret_cast<const float4*>(src + 8 + q4 * 4);
      v1[q4 * 4 + 0] = (short)f2bf(f.x); v1[q4 * 4 + 1] = (short)f2bf(f.y);
      v1[q4 * 4 + 2] = (short)f2bf(f.z); v1[q4 * 4 + 3] = (short)f2bf(f.w);
    }
    *reinterpret_cast<bfrag*>(&tile[cl * 72 + pl]) = v0;
    *reinterpret_cast<bfrag*>(&tile[cl * 72 + pl + 8]) = v1;
  }
  __syncthreads();
  {
    const int pl = t >> 2, cl = (t & 3) * 16;
    bfrag o0, o1;
#pragma unroll
    for (int e = 0; e < 8; ++e) o0[e] = (short)tile[(cl + e) * 72 + pl];
#pragma unroll
    for (int e = 0; e < 8; ++e) o1[e] = (short)tile[(cl + 8 + e) * 72 + pl];
    const int P = pb + pl, ch0 = cb + cl;
    const int ti = P >> 7, pit = P & 127;
    const int w = pit >> 5, p32 = pit & 31;
    const int j = (p32 >> 2) & 1;
    const int r = ((p32 >> 3) << 2) | (p32 & 3);
    const int s0 = ch0 >> 5, kh0 = (ch0 >> 3) & 3;
    const int ch1 = ch0 + 8, s1 = ch1 >> 5, kh1 = (ch1 >> 3) & 3;
    *reinterpret_cast<bfrag*>(xb + faddr(b, ti, w, j, s0, r + 16 * kh0)) = o0;
    *reinterpret_cast<bfrag*>(xb + faddr(b, ti, w, j, s1, r + 16 * kh1)) = o1;
  }
}

// ---------------- prep: pack W into MFMA fragment order ----------------
__global__ __launch_bounds__(256) void k_wpack(const float* __restrict__ w,
                                               unsigned short* __restrict__ wp) {
  const int g = blockIdx.x * 256 + threadIdx.x;
  if (g >= 216 * 64) return;
  const int frag = g >> 6, lane = g & 63;
  const int mb = frag / 24, r = frag % 24, s = r >> 2, i = r & 3;
  const int row = mb * 64 + i * 16 + (lane & 15);
  const int col = s * 32 + (lane >> 4) * 8;
  const float* src = w + (size_t)row * CC + col;
  float4 f0 = *reinterpret_cast<const float4*>(src);
  float4 f1 = *reinterpret_cast<const float4*>(src + 4);
  us4 o0, o1;
  o0[0] = f2bf(f0.x); o0[1] = f2bf(f0.y); o0[2] = f2bf(f0.z); o0[3] = f2bf(f0.w);
  o1[0] = f2bf(f1.x); o1[1] = f2bf(f1.y); o1[2] = f2bf(f1.z); o1[3] = f2bf(f1.w);
  *reinterpret_cast<us4*>(wp + (size_t)g * 8) = o0;
  *reinterpret_cast<us4*>(wp + (size_t)g * 8 + 4) = o1;
}

// ---------------- qkv GEMM: zero-LDS/barrier, full-line stores, mb SPLIT x3 ----------------
// grid (64, 3, NB): group g handles mb = g*3..g*3+2 -> 3x the waves in flight
// (48 waves/CU of work vs 16), deeper store/load overlap. B-frags re-read per
// group from L3 (cheap).
__global__ __launch_bounds__(512, 4) void k_gemm_qkv(const unsigned short* __restrict__ Wp,
                                                     const unsigned short* __restrict__ XB,
                                                     unsigned short* __restrict__ Y) {
  const int nb = blockIdx.x;  // 64 double-tiles of 256 px
  const int g  = blockIdx.y;  // 3 mb-groups of 3
  const int b  = blockIdx.z;
  const int tid = threadIdx.x;
  const int wave = tid >> 6, lane = tid & 63;
  const int lrow = lane & 15;
  const int q8 = (lane >> 4) * 8;
  const int tile = nb * 2 + (wave >> 2), w = wave & 3;

  bfrag bq[2][6];
#pragma unroll
  for (int j = 0; j < 2; ++j)
#pragma unroll
    for (int s = 0; s < 6; ++s)
      bq[j][s] = *reinterpret_cast<const bfrag*>(XB + faddr(b, tile, w, j, s, lane));

  const f32x4 z4 = {0.f, 0.f, 0.f, 0.f};
#pragma unroll 1
  for (int m3 = 0; m3 < 3; ++m3) {
    const int mb = g * 3 + m3;
    const unsigned short* Wb = Wp + (size_t)mb * 24 * 512;
    f32x4 acc[4][2];
#pragma unroll
    for (int i = 0; i < 4; ++i) { acc[i][0] = z4; acc[i][1] = z4; }
#pragma unroll
    for (int s = 0; s < 6; ++s) {
      bfrag af[4];
#pragma unroll
      for (int i = 0; i < 4; ++i)
        af[i] = *reinterpret_cast<const bfrag*>(Wb + ((s * 4 + i) * 64 + lane) * 8);
#pragma unroll
      for (int i = 0; i < 4; ++i) {
        acc[i][0] = MFMA16(bq[0][s], af[i], acc[i][0]);
        acc[i][1] = MFMA16(bq[1][s], af[i], acc[i][1]);
      }
    }
    unsigned short* Yb = Y + ((size_t)b * C3 + mb * 64) * HWP + tile * 128 + w * 32 + q8;
#pragma unroll
    for (int i = 0; i < 4; ++i) {
      uint4 pk;
      pk.x = pk2(acc[i][0][0], acc[i][0][1]);
      pk.y = pk2(acc[i][0][2], acc[i][0][3]);
      pk.z = pk2(acc[i][1][0], acc[i][1][1]);
      pk.w = pk2(acc[i][1][2], acc[i][1][3]);
      *reinterpret_cast<uint4*>(Yb + (size_t)(i * 16 + lrow) * HWP) = pk;
    }
  }
}

// ---------------- depthwise 3x3 SAME on q,k: stencil reuse + shfl halos ----------------
__global__ __launch_bounds__(256) void k_dwconv(const unsigned short* __restrict__ in,
                                                const float* __restrict__ wd,
                                                unsigned short* __restrict__ outb) {
  const int band = blockIdx.x;   // 4 bands of 32 output rows
  const int ch = blockIdx.y;     // 384 (q,k channels)
  const int b = blockIdx.z;
  const int t = threadIdx.x;
  const unsigned short* ip = in + ((size_t)b * C3 + ch) * HWP;
  const float* w = wd + ch * 9;
  const int xg = t & 15, x0 = xg * 8;
  const int y0 = band * 32 + (t >> 4) * 2;

  float c[4][8];
#pragma unroll
  for (int r = 0; r < 4; ++r) {
    const int yy = y0 - 1 + r;
    if (yy < 0 || yy > 127) {
#pragma unroll
      for (int e = 0; e < 8; ++e) c[r][e] = 0.f;
    } else {
      bfrag v = *reinterpret_cast<const bfrag*>(ip + yy * 128 + x0);
#pragma unroll
      for (int e = 0; e < 8; ++e) c[r][e] = bf2f_s(v[e]);
    }
  }
  float L[4], R[4];
#pragma unroll
  for (int r = 0; r < 4; ++r) {
    const float l = __shfl_up(c[r][7], 1);
    L[r] = (xg == 0) ? 0.f : l;
    const float rr = __shfl_down(c[r][0], 1);
    R[r] = (xg == 15) ? 0.f : rr;
  }
  unsigned short* op = outb + ((size_t)b * 384 + ch) * HWP;
#pragma unroll
  for (int i = 0; i < 2; ++i) {
    float acc[8];
#pragma unroll
    for (int e = 0; e < 8; ++e) acc[e] = 0.f;
#pragma unroll
    for (int dy = 0; dy < 3; ++dy) {
      const int r = i + dy;
      const float wl = w[dy * 3 + 0], wc = w[dy * 3 + 1], wr = w[dy * 3 + 2];
      acc[0] += wl * L[r] + wc * c[r][0] + wr * c[r][1];
#pragma unroll
      for (int e = 1; e < 7; ++e) acc[e] += wl * c[r][e - 1] + wc * c[r][e] + wr * c[r][e + 1];
      acc[7] += wl * c[r][6] + wc * c[r][7] + wr * R[r];
    }
    bfrag o;
#pragma unroll
    for (int e = 0; e < 8; ++e) o[e] = (short)f2bf(acc[e]);
    *reinterpret_cast<bfrag*>(op + (size_t)(y0 + i) * 128 + x0) = o;
  }
}

// ---------------- gram from QKD [b][384][HWP] ----------------
__global__ __launch_bounds__(256) void k_gram(const unsigned short* __restrict__ Qd,
                                              float* __restrict__ S,
                                              float* __restrict__ ssq) {
  const int chunk = blockIdx.x;
  const int h = blockIdx.y, b = blockIdx.z;
  const int tid = threadIdx.x, wave = tid >> 6, lane = tid & 63;
  const int lrow = lane & 15, lk8 = (lane >> 4) * 8;
  const unsigned short* qb = Qd + ((size_t)b * 384 + h * 24) * HWP;
  const unsigned short* kb = qb + (size_t)192 * HWP;
  const int p0 = chunk * 1024 + wave * 256;
  f32x4 acc[2][2];
  const f32x4 z4 = {0.f, 0.f, 0.f, 0.f};
#pragma unroll
  for (int i = 0; i < 2; ++i)
#pragma unroll
    for (int j = 0; j < 2; ++j) acc[i][j] = z4;
  float sq[2] = {0.f, 0.f}, sk[2] = {0.f, 0.f};
  for (int s = 0; s < 8; ++s) {
    const int pp = p0 + s * 32 + lk8;
    bfrag aq[2], bk[2];
#pragma unroll
    for (int i = 0; i < 2; ++i) {
      aq[i] = *reinterpret_cast<const bfrag*>(qb + (size_t)(i * 16 + lrow) * HWP + pp);
      bk[i] = *reinterpret_cast<const bfrag*>(kb + (size_t)(i * 16 + lrow) * HWP + pp);
    }
#pragma unroll
    for (int i = 0; i < 2; ++i) {
#pragma unroll
      for (int e = 0; e < 8; ++e) {
        float qv = bf2f_s(aq[i][e]); sq[i] += qv * qv;
        float kv = bf2f_s(bk[i][e]); sk[i] += kv * kv;
      }
    }
#pragma unroll
    for (int i = 0; i < 2; ++i)
#pragma unroll
      for (int j = 0; j < 2; ++j) acc[i][j] = MFMA16(aq[i], bk[j], acc[i][j]);
  }
  float* Sb = S + (size_t)(b * 8 + h) * 1024;
  const int lr4 = (lane >> 4) * 4;
#pragma unroll
  for (int i = 0; i < 2; ++i)
#pragma unroll
    for (int j = 0; j < 2; ++j)
#pragma unroll
      for (int r = 0; r < 4; ++r)
        atomicAdd(&Sb[(i * 16 + lr4 + r) * 32 + j * 16 + lrow], acc[i][j][r]);
#pragma unroll
  for (int i = 0; i < 2; ++i) {
    float v = sq[i];
    v += __shfl_xor(v, 16); v += __shfl_xor(v, 32);
    float wv = sk[i];
    wv += __shfl_xor(wv, 16); wv += __shfl_xor(wv, 32);
    const int c = i * 16 + lrow;
    if ((lane >> 4) == 0 && c < 24) {
      atomicAdd(&ssq[b * 384 + h * 24 + c], v);
      atomicAdd(&ssq[b * 384 + 192 + h * 24 + c], wv);
    }
  }
}

// ---------------- fused dwconv(v) + transpose -> VT in FRAG order (NATURAL px map) ----
__global__ __launch_bounds__(256) void k_dwvt(const unsigned short* __restrict__ QKV,
                                              const float* __restrict__ wd,
                                              unsigned short* __restrict__ VTo) {
  __shared__ unsigned short tile[64 * 72];
  const int pb = blockIdx.x * 64, cb = blockIdx.y * 64, b = blockIdx.z;
  const int t = threadIdx.x;
  const int y = pb >> 7;
  const int xs = pb & 127;
  {
    const int cl = t >> 2, ps = (t & 3) * 16;
    const int gc = 384 + cb + cl;
    const unsigned short* ip = QKV + ((size_t)b * C3 + gc) * HWP;
    const float* w = wd + gc * 9;
    const int x0 = xs + ps;
    float acc[16];
#pragma unroll
    for (int e = 0; e < 16; ++e) acc[e] = 0.f;
#pragma unroll
    for (int dy = 0; dy < 3; ++dy) {
      int yy = y + dy - 1;
      if (yy < 0 || yy > 127) continue;
      const unsigned short* row = ip + yy * 128;
      bfrag v0 = *reinterpret_cast<const bfrag*>(row + x0);
      bfrag v1 = *reinterpret_cast<const bfrag*>(row + x0 + 8);
      float c[16];
#pragma unroll
      for (int e = 0; e < 8; ++e) { c[e] = bf2f_s(v0[e]); c[8 + e] = bf2f_s(v1[e]); }
      float left  = (x0 > 0)   ? bf2f(row[x0 - 1])  : 0.f;
      float right = (x0 < 112) ? bf2f(row[x0 + 16]) : 0.f;
      float wl = w[dy * 3 + 0], wc = w[dy * 3 + 1], wr = w[dy * 3 + 2];
      acc[0] += wl * left + wc * c[0] + wr * c[1];
#pragma unroll
      for (int e = 1; e < 15; ++e) acc[e] += wl * c[e - 1] + wc * c[e] + wr * c[e + 1];
      acc[15] += wl * c[14] + wc * c[15] + wr * right;
    }
    bfrag o0, o1;
#pragma unroll
    for (int e = 0; e < 8; ++e) { o0[e] = (short)f2bf(acc[e]); o1[e] = (short)f2bf(acc[8 + e]); }
    *reinterpret_cast<bfrag*>(&tile[cl * 72 + ps]) = o0;
    *reinterpret_cast<bfrag*>(&tile[cl * 72 + ps + 8]) = o1;
  }
  __syncthreads();
  {
    const int pl = t >> 2, cs = (t & 3) * 16;
    bfrag o0, o1;
#pragma unroll
    for (int e = 0; e < 8; ++e) o0[e] = (short)tile[(cs + e) * 72 + pl];
#pragma unroll
    for (int e = 0; e < 8; ++e) o1[e] = (short)tile[(cs + 8 + e) * 72 + pl];
    const int P = pb + pl, ch0 = cb + cs;
    const int ti = P >> 7, pit = P & 127;
    const int w = pit >> 5, j = (pit >> 4) & 1, pxl = pit & 15;
    const int s0 = ch0 >> 5, kh0 = (ch0 >> 3) & 3;
    const int ch1 = ch0 + 8, s1 = ch1 >> 5, kh1 = (ch1 >> 3) & 3;
    *reinterpret_cast<bfrag*>(VTo + faddr(b, ti, w, j, s0, pxl + 16 * kh0)) = o0;
    *reinterpret_cast<bfrag*>(VTo + faddr(b, ti, w, j, s1, pxl + 16 * kh1)) = o1;
  }
}

// ---------------- softmax + M = wproj @ blockdiag(attn), written PACKED ----------------
__global__ __launch_bounds__(64) void k_attn(const float* __restrict__ S,
                                             const float* __restrict__ ssq,
                                             const float* __restrict__ wproj,
                                             const float* __restrict__ temp,
                                             unsigned short* __restrict__ Mp) {
  const int h = blockIdx.x, b = blockIdx.y;
  __shared__ float A[24][25];
  __shared__ float nq[24], nk[24];
  const float* Sb = S + (size_t)(b * 8 + h) * 1024;
  const float* sq = ssq + b * 384 + h * 24;
  const float* sk = ssq + b * 384 + 192 + h * 24;
  const int t = threadIdx.x;
  if (t < 24) {
    nq[t] = fmaxf(sqrtf(sq[t]), 1e-12f);
    nk[t] = fmaxf(sqrtf(sk[t]), 1e-12f);
  }
  __syncthreads();
  if (t < 24) {
    const float tp = temp[h];
    float row[24];
    float mx = -1e30f;
#pragma unroll
    for (int d = 0; d < 24; ++d) {
      row[d] = Sb[t * 32 + d] / (nq[t] * nk[d]) * tp;
      mx = fmaxf(mx, row[d]);
    }
    float s = 0.f;
#pragma unroll
    for (int d = 0; d < 24; ++d) { row[d] = __expf(row[d] - mx); s += row[d]; }
    const float inv = 1.f / s;
#pragma unroll
    for (int d = 0; d < 24; ++d) A[t][d] = row[d] * inv;
  }
  __syncthreads();
  for (int idx = t; idx < 192 * 24; idx += 64) {
    const int o = idx / 24, dd = idx % 24;
    const float* wrow = wproj + o * 192 + h * 24;
    float a = 0.f;
#pragma unroll
    for (int cc = 0; cc < 24; ++cc) a += wrow[cc] * A[cc][dd];
    const int c = h * 24 + dd;
    const int mb = o >> 6, i = (o >> 4) & 3, lr = o & 15;
    const int s = c >> 5, hi = (c >> 3) & 3, e = c & 7;
    const int off = ((mb * 24 + s * 4 + i) * 64 + hi * 16 + lr) * 8 + e;
    Mp[(size_t)b * CC * CC + off] = f2bf(a);
  }
}

// ---------------- out GEMM: zero-LDS, zero-barrier (frag-order VT, natural px) ----------
__global__ __launch_bounds__(512, 4) void k_gemm_out(const unsigned short* __restrict__ Mp,
                                                     const unsigned short* __restrict__ VB,
                                                     float* __restrict__ out) {
  const int nb = blockIdx.x;  // 64 double-tiles of 256 px
  const int b  = blockIdx.y;
  const int tid = threadIdx.x;
  const int wave = tid >> 6, lane = tid & 63;
  const int lrow = lane & 15, lr4 = (lane >> 4) * 4;
  const int tile = nb * 2 + (wave >> 2), w = wave & 3;

  bfrag bq[2][6];
#pragma unroll
  for (int j = 0; j < 2; ++j)
#pragma unroll
    for (int s = 0; s < 6; ++s)
      bq[j][s] = *reinterpret_cast<const bfrag*>(VB + faddr(b, tile, w, j, s, lane));

  const f32x4 z4 = {0.f, 0.f, 0.f, 0.f};
#pragma unroll 1
  for (int mb = 0; mb < 3; ++mb) {
    const unsigned short* Mb = Mp + (size_t)b * CC * CC + (size_t)mb * 24 * 512;
    bfrag af[6][4];
#pragma unroll
    for (int s = 0; s < 6; ++s)
#pragma unroll
      for (int i = 0; i < 4; ++i)
        af[s][i] = *reinterpret_cast<const bfrag*>(Mb + ((s * 4 + i) * 64 + lane) * 8);

    f32x4 acc[4][2];
#pragma unroll
    for (int i = 0; i < 4; ++i) { acc[i][0] = z4; acc[i][1] = z4; }
#pragma unroll
    for (int s = 0; s < 6; ++s) {
#pragma unroll
      for (int i = 0; i < 4; ++i) {
        acc[i][0] = MFMA16(bq[0][s], af[s][i], acc[i][0]);  // D[px][ch]
        acc[i][1] = MFMA16(bq[1][s], af[s][i], acc[i][1]);
      }
    }
    float* Ob = out + ((size_t)b * CC + mb * 64) * HW + tile * 128 + w * 32;
#pragma unroll
    for (int i = 0; i < 4; ++i) {
      float* rp = Ob + (size_t)(i * 16 + lrow) * HW;
#pragma unroll
      for (int j = 0; j < 2; ++j)
        *reinterpret_cast<f32x4*>(rp + j * 16 + lr4) = acc[i][j];
    }
  }
}

extern "C" void kernel_launch(void* const* d_in, const int* in_sizes, int n_in,
                              void* d_out, int out_size, void* d_ws, size_t ws_size,
                              hipStream_t stream) {
  const float* x      = (const float*)d_in[0];
  const float* w_qkv  = (const float*)d_in[1];
  const float* w_dw   = (const float*)d_in[2];
  const float* w_proj = (const float*)d_in[3];
  const float* temp   = (const float*)d_in[4];
  float* out = (float*)d_out;
  char* ws = (char*)d_ws;

  unsigned short* XB   = (unsigned short*)(ws + OFF_XT);
  unsigned short* VB   = (unsigned short*)(ws + OFF_XT);  // reuse: XB dead after qkv GEMM
  unsigned short* WP   = (unsigned short*)(ws + OFF_WQ);
  unsigned short* QKV  = (unsigned short*)(ws + OFF_QKV);
  unsigned short* QKD  = (unsigned short*)(ws + OFF_QKD);
  float* S   = (float*)(ws + OFF_S);
  float* SSQ = (float*)(ws + OFF_SSQ);
  unsigned short* MP  = (unsigned short*)(ws + OFF_M);

  hipMemsetAsync(ws + OFF_S, 0, SZ_S + SZ_SSQ, stream);
  k_wpack<<<54, 256, 0, stream>>>(w_qkv, WP);
  k_xt<<<dim3(HW / 64, CC / 64, NB), 256, 0, stream>>>(x, XB);
  k_gemm_qkv<<<dim3(64, 3, NB), 512, 0, stream>>>(WP, XB, QKV);
  k_dwconv<<<dim3(4, 384, NB), 256, 0, stream>>>(QKV, w_dw, QKD);
  k_dwvt<<<dim3(HW / 64, 3, NB), 256, 0, stream>>>(QKV, w_dw, VB);
  k_gram<<<dim3(16, NH, NB), 256, 0, stream>>>(QKD, S, SSQ);
  k_attn<<<dim3(NH, NB), 64, 0, stream>>>(S, SSQ, w_proj, temp, MP);
  k_gemm_out<<<dim3(64, NB), 512, 0, stream>>>(MP, VB, out);
}